// Round 8
// baseline (357.163 us; speedup 1.0000x reference)
//
#include <hip/hip_runtime.h>
#include <math.h>

#define N 4096
#define TOTAL (N * N)
#define MED_RANK 8388607u  // (TOTAL-1)/2
#define NSHARD 8

// monotonic float->uint key
__device__ __forceinline__ unsigned fkey(float f) {
    unsigned u = __float_as_uint(f);
    return (u & 0x80000000u) ? ~u : (u | 0x80000000u);
}

// Sobel + products — EXACT round-5-validated fp32 sequence. Do not alter.
__device__ __forceinline__ void sobel3(float A, float B, float C,
                                       float D, float F,
                                       float G, float H, float I,
                                       float& pxx, float& pyy, float& pxy) {
    float ix = __fmul_rn(-1.0f, A);
    ix = __fadd_rn(ix, C);
    ix = __fadd_rn(ix, __fmul_rn(-2.0f, D));
    ix = __fadd_rn(ix, __fmul_rn(2.0f, F));
    ix = __fadd_rn(ix, __fmul_rn(-1.0f, G));
    ix = __fadd_rn(ix, I);
    float iy = __fmul_rn(-1.0f, A);
    iy = __fadd_rn(iy, __fmul_rn(-2.0f, B));
    iy = __fadd_rn(iy, __fmul_rn(-1.0f, C));
    iy = __fadd_rn(iy, G);
    iy = __fadd_rn(iy, __fmul_rn(2.0f, H));
    iy = __fadd_rn(iy, I);
    pxx = __fmul_rn(ix, ix);
    pyy = __fmul_rn(iy, iy);
    pxy = __fmul_rn(ix, iy);
}

// ============================================================
// K1: byte-identical to round 7 (156 µs champion: RT=32, parity-split
// lh, RLE hist, reg-staged async row pipeline, sharded flush).
// ============================================================
constexpr int RT = 32;
constexpr int W = 512;

__global__ __launch_bounds__(256) void k1_kernel(
    const float* __restrict__ x, const float* __restrict__ gk,
    float* __restrict__ R, unsigned* __restrict__ hist1) {
    __shared__ __align__(16) float xs[4][524];
    __shared__ __align__(16) float ps[3][520];
    __shared__ unsigned lh[4096];  // parity-split: [bin*2 + (tid&1)]

    const int tid = threadIdx.x;
    const int bx = blockIdx.x * W;
    const int by = blockIdx.y * RT;
    const unsigned par = (unsigned)(tid & 1);

    for (int i = tid; i < 4096; i += 256) lh[i] = 0;

    float w49[49];
    #pragma unroll
    for (int k = 0; k < 49; k++) w49[k] = gk[k];

    float2 a0[7], a1[7], a2[7];
    #pragma unroll
    for (int k = 0; k < 7; k++) {
        a0[k] = make_float2(0.0f, 0.0f);
        a1[k] = make_float2(0.0f, 0.0f);
        a2[k] = make_float2(0.0f, 0.0f);
    }

    // RLE histogram state (per column owned by this thread)
    unsigned curx = 0xFFFFFFFFu, cntx = 0;
    unsigned cury = 0xFFFFFFFFu, cnty = 0;

    const int e_m = 2 * tid;
    const int col_m = bx - 5 + e_m;
    const int e_t = 2 * (tid + 256);
    const int col_t = bx - 5 + e_t;
    const bool has_t = (tid < 6);

#define ISSUE(arow, m0, m1, t0, t1)                                      \
    {                                                                    \
        m0 = 0.0f; m1 = 0.0f; t0 = 0.0f; t1 = 0.0f;                      \
        if ((unsigned)(arow) < N) {                                      \
            const float* xr = x + (size_t)(arow) * N;                    \
            if ((unsigned)col_m < N) m0 = xr[col_m];                     \
            if ((unsigned)(col_m + 1) < N) m1 = xr[col_m + 1];           \
            if (has_t) {                                                 \
                if ((unsigned)col_t < N) t0 = xr[col_t];                 \
                if ((unsigned)(col_t + 1) < N) t1 = xr[col_t + 1];       \
            }                                                            \
        }                                                                \
    }

#define WRITE_SLOT(slot, m0, m1, t0, t1)                                 \
    {                                                                    \
        *(float2*)&xs[slot][e_m] = make_float2(m0, m1);                  \
        if (has_t) *(float2*)&xs[slot][e_t] = make_float2(t0, t1);       \
    }

    float pm0, pm1, pt0, pt1;
    {
        float r4m0, r4m1, r4t0, r4t1;
        float r3m0, r3m1, r3t0, r3t1;
        float r2m0, r2m1, r2t0, r2t1;
        ISSUE(by - 4, r4m0, r4m1, r4t0, r4t1)
        ISSUE(by - 3, r3m0, r3m1, r3t0, r3t1)
        ISSUE(by - 2, r2m0, r2m1, r2t0, r2t1)
        ISSUE(by - 1, pm0, pm1, pt0, pt1)
        WRITE_SLOT(0, r4m0, r4m1, r4t0, r4t1)
        WRITE_SLOT(1, r3m0, r3m1, r3t0, r3t1)
        WRITE_SLOT(2, r2m0, r2m1, r2t0, r2t1)
    }
    __syncthreads();

    for (int it = 0; it < RT + 6; ++it) {
        const int ri = by - 3 + it;
        {
            const int s0 = it & 3, s1 = (it + 1) & 3, s2 = (it + 2) & 3;
            const bool rowv = (unsigned)ri < N;
            for (int t = tid; t < 260; t += 256) {
                int e = 2 * t;
                float2 r0a = *(const float2*)&xs[s0][e];
                float2 r0b = *(const float2*)&xs[s0][e + 2];
                float2 r1a = *(const float2*)&xs[s1][e];
                float2 r1b = *(const float2*)&xs[s1][e + 2];
                float2 r2a = *(const float2*)&xs[s2][e];
                float2 r2b = *(const float2*)&xs[s2][e + 2];
                float pxx0 = 0.0f, pyy0 = 0.0f, pxy0 = 0.0f;
                float pxx1 = 0.0f, pyy1 = 0.0f, pxy1 = 0.0f;
                if (rowv) {
                    if ((unsigned)(bx + 2 * t - 4) < N)
                        sobel3(r0a.x, r0a.y, r0b.x, r1a.x, r1b.x,
                               r2a.x, r2a.y, r2b.x, pxx0, pyy0, pxy0);
                    if ((unsigned)(bx + 2 * t - 3) < N)
                        sobel3(r0a.y, r0b.x, r0b.y, r1a.y, r1b.y,
                               r2a.y, r2b.x, r2b.y, pxx1, pyy1, pxy1);
                }
                *(float2*)&ps[0][e] = make_float2(pxx0, pxx1);
                *(float2*)&ps[1][e] = make_float2(pyy0, pyy1);
                *(float2*)&ps[2][e] = make_float2(pxy0, pxy1);
            }
        }
        __syncthreads();  // B2: ps ready; all xs reads of this iter done

        if (it <= RT + 4) WRITE_SLOT((it + 3) & 3, pm0, pm1, pt0, pt1)
        if (it < RT + 4) ISSUE(by + it, pm0, pm1, pt0, pt1)

        float q0[10], q1[10], q2[10];
        #pragma unroll
        for (int i = 0; i < 5; i++) {
            float2 v0 = *(const float2*)&ps[0][2 * (tid + i)];
            float2 v1 = *(const float2*)&ps[1][2 * (tid + i)];
            float2 v2 = *(const float2*)&ps[2][2 * (tid + i)];
            q0[2 * i] = v0.x; q0[2 * i + 1] = v0.y;
            q1[2 * i] = v1.x; q1[2 * i + 1] = v1.y;
            q2[2 * i] = v2.x; q2[2 * i + 1] = v2.y;
        }
        #pragma unroll
        for (int k = 0; k < 7; k++) {
            float t0x = a0[k].x, t0y = a0[k].y;
            float t1x = a1[k].x, t1y = a1[k].y;
            float t2x = a2[k].x, t2y = a2[k].y;
            #pragma unroll
            for (int dx = 0; dx < 7; dx++) {
                float w = w49[k * 7 + dx];
                t0x = __fadd_rn(t0x, __fmul_rn(w, q0[1 + dx]));
                t0y = __fadd_rn(t0y, __fmul_rn(w, q0[2 + dx]));
                t1x = __fadd_rn(t1x, __fmul_rn(w, q1[1 + dx]));
                t1y = __fadd_rn(t1y, __fmul_rn(w, q1[2 + dx]));
                t2x = __fadd_rn(t2x, __fmul_rn(w, q2[1 + dx]));
                t2y = __fadd_rn(t2y, __fmul_rn(w, q2[2 + dx]));
            }
            a0[k] = make_float2(t0x, t0y);
            a1[k] = make_float2(t1x, t1y);
            a2[k] = make_float2(t2x, t2y);
        }

        int r = ri - 3;
        if (r >= by) {
            float Rx, Ry;
            {
                float sx2 = a0[6].x, sy2 = a1[6].x, sxy = a2[6].x;
                float tr = __fadd_rn(sx2, sy2);
                float e = __fsub_rn(__fmul_rn(sx2, sy2), __fmul_rn(sxy, sxy));
                float t3 = __fmul_rn(__fmul_rn(0.05f, tr), tr);
                Rx = __fsub_rn(e, t3);
            }
            {
                float sx2 = a0[6].y, sy2 = a1[6].y, sxy = a2[6].y;
                float tr = __fadd_rn(sx2, sy2);
                float e = __fsub_rn(__fmul_rn(sx2, sy2), __fmul_rn(sxy, sxy));
                float t3 = __fmul_rn(__fmul_rn(0.05f, tr), tr);
                Ry = __fsub_rn(e, t3);
            }
            *(float2*)&R[(size_t)r * N + bx + 2 * tid] = make_float2(Rx, Ry);
            // RLE histogram: emit only on bin change
            unsigned kx = fkey(Rx) >> 21;
            unsigned ky = fkey(Ry) >> 21;
            if (kx == curx) { cntx++; }
            else { if (cntx) atomicAdd(&lh[(curx << 1) | par], cntx); curx = kx; cntx = 1; }
            if (ky == cury) { cnty++; }
            else { if (cnty) atomicAdd(&lh[(cury << 1) | par], cnty); cury = ky; cnty = 1; }
        }
        #pragma unroll
        for (int k = 6; k > 0; k--) { a0[k] = a0[k - 1]; a1[k] = a1[k - 1]; a2[k] = a2[k - 1]; }
        a0[0] = make_float2(0.0f, 0.0f);
        a1[0] = make_float2(0.0f, 0.0f);
        a2[0] = make_float2(0.0f, 0.0f);

        __syncthreads();  // B1
    }

    // flush RLE tails, then the block histogram (sharded + rotated)
    if (cntx) atomicAdd(&lh[(curx << 1) | par], cntx);
    if (cnty) atomicAdd(&lh[(cury << 1) | par], cnty);
    __syncthreads();
    {
        const unsigned shard = (blockIdx.x + blockIdx.y) & (NSHARD - 1);
        const int rot = (int)((blockIdx.y & 31u) << 6);
        for (int i = tid; i < 2048; i += 256) {
            int r = (i + rot) & 2047;
            unsigned c = lh[2 * r] + lh[2 * r + 1];
            if (c) atomicAdd(&hist1[shard * 2048 + r], c);
        }
    }
#undef ISSUE
#undef WRITE_SLOT
}

// ============================================================
// block_select (plain, non-sharded histogram).
// ============================================================
__device__ void block_select(const unsigned* hist, int nbins,
                             unsigned rank_in, unsigned oldpref, int shift,
                             unsigned* sc, unsigned* sres,
                             unsigned& pref_out, unsigned& rank_out) {
    const int tid = threadIdx.x;
    const int bpt = nbins >> 8;

    unsigned cnt[8];
    unsigned s = 0;
    for (int i = 0; i < bpt; i++) { cnt[i] = hist[tid * bpt + i]; s += cnt[i]; }
    sc[tid] = s;
    __syncthreads();
    for (int off = 1; off < 256; off <<= 1) {
        unsigned v = (tid >= off) ? sc[tid - off] : 0u;
        __syncthreads();
        sc[tid] += v;
        __syncthreads();
    }
    const unsigned incl = sc[tid];
    const unsigned excl = incl - s;

    if (rank_in >= excl && rank_in < incl) {
        unsigned r = rank_in - excl;
        for (int i = 0; i < bpt; i++) {
            if (r < cnt[i]) {
                sres[0] = oldpref | ((unsigned)(tid * bpt + i) << shift);
                sres[1] = r;
                break;
            }
            r -= cnt[i];
        }
    }
    __syncthreads();
    pref_out = sres[0];
    rank_out = sres[1];
    __syncthreads();
}

// block_select over an NSHARD-way sharded histogram.
__device__ void block_select_sh8(const unsigned* hist, int nbins,
                                 unsigned rank_in, unsigned oldpref, int shift,
                                 unsigned* sc, unsigned* sres,
                                 unsigned& pref_out, unsigned& rank_out) {
    const int tid = threadIdx.x;
    const int bpt = nbins >> 8;

    unsigned cnt[8];
    unsigned s = 0;
    for (int i = 0; i < bpt; i++) {
        unsigned c = 0;
        #pragma unroll
        for (int sh = 0; sh < NSHARD; sh++) c += hist[sh * nbins + tid * bpt + i];
        cnt[i] = c;
        s += c;
    }
    sc[tid] = s;
    __syncthreads();
    for (int off = 1; off < 256; off <<= 1) {
        unsigned v = (tid >= off) ? sc[tid - off] : 0u;
        __syncthreads();
        sc[tid] += v;
        __syncthreads();
    }
    const unsigned incl = sc[tid];
    const unsigned excl = incl - s;

    if (rank_in >= excl && rank_in < incl) {
        unsigned r = rank_in - excl;
        for (int i = 0; i < bpt; i++) {
            if (r < cnt[i]) {
                sres[0] = oldpref | ((unsigned)(tid * bpt + i) << shift);
                sres[1] = r;
                break;
            }
            r -= cnt[i];
        }
    }
    __syncthreads();
    pref_out = sres[0];
    rank_out = sres[1];
    __syncthreads();
}

// wave-aggregated LDS histogram add: one atomic for the leader's bin
// (the common case: ~46% of values share one bin), individual atomics
// for dissenting lanes. Counts exactly preserved.
__device__ __forceinline__ void agg_lds_add(unsigned* lh, unsigned bin, bool active) {
    unsigned long long act = __ballot(active);
    if (act == 0ull) return;
    int leader = __builtin_ctzll(act);
    unsigned lbin = __shfl(bin, leader);
    unsigned long long sm = __ballot(active && bin == lbin);
    if (active) {
        if (bin == lbin) {
            if ((int)(threadIdx.x & 63) == leader)
                atomicAdd(&lh[bin], (unsigned)__popcll(sm));
        } else {
            atomicAdd(&lh[bin], 1u);
        }
    }
}

// ============================================================
// H2': per-block select1 (sharded hist1), then stream R ONCE:
//  - LDS coarse hist2 (bits 20..10 of pref1-matching keys), sharded flush
//  - fine 2M-bin GLOBAL hist (bits 20..0 of matching keys) —
//    fire-and-forget atomics, ~4 counts/bin, no contention.
// This makes the third radix pass (h3's full 64MB stream) unnecessary:
// select3's 1024 bins are a row of `fine`.
// ============================================================
__global__ __launch_bounds__(256) void h2_kernel(
    const float4* __restrict__ R4, const unsigned* __restrict__ hist1,
    unsigned* __restrict__ hist2, unsigned* __restrict__ fine,
    unsigned* __restrict__ state) {
    __shared__ unsigned lh[2048];
    __shared__ unsigned sc[256];
    __shared__ unsigned sres[2];
    const int tid = threadIdx.x;

    unsigned pref1, rank1;
    block_select_sh8(hist1, 2048, MED_RANK, 0u, 21, sc, sres, pref1, rank1);
    if (blockIdx.x == 0 && tid == 0) { state[6] = pref1; state[7] = rank1; }

    for (int i = tid; i < 2048; i += 256) lh[i] = 0;
    __syncthreads();

    const int total4 = TOTAL / 4;
    const int stride = (int)gridDim.x * 256;
    for (int i = (int)blockIdx.x * 256 + tid; i < total4; i += stride) {
        float4 v = R4[i];
        unsigned kk[4];
        kk[0] = fkey(v.x); kk[1] = fkey(v.y);
        kk[2] = fkey(v.z); kk[3] = fkey(v.w);
        #pragma unroll
        for (int c = 0; c < 4; c++) {
            unsigned k = kk[c];
            bool m = (k & 0xFFE00000u) == pref1;
            agg_lds_add(lh, (k >> 10) & 0x7FFu, m);
            if (m) atomicAdd(&fine[k & 0x1FFFFFu], 1u);  // fire-and-forget
        }
    }
    __syncthreads();
    {
        const unsigned shard = blockIdx.x & (NSHARD - 1);
        const int rot = (int)((blockIdx.x & 31u) << 6);
        for (int i = tid; i < 2048; i += 256) {
            int r = (i + rot) & 2047;
            unsigned c = lh[r];
            if (c) atomicAdd(&hist2[shard * 2048 + r], c);
        }
    }
}

// ============================================================
// FSEL: single block. select2 over sharded hist2 (bits 20..10), then
// select3 directly over the 1024-entry fine row (bits 9..0).
// Writes state[2] = median float bits.
// ============================================================
__global__ __launch_bounds__(256) void fsel_kernel(
    const unsigned* __restrict__ hist2, const unsigned* __restrict__ fine,
    unsigned* __restrict__ state) {
    __shared__ unsigned sc[256];
    __shared__ unsigned sres[2];

    unsigned pref2, rank2;
    block_select_sh8(hist2, 2048, state[7], state[6], 10, sc, sres, pref2, rank2);

    const unsigned row = (pref2 >> 10) & 0x7FFu;
    unsigned pref3, rank3;
    block_select(fine + (size_t)row * 1024, 1024, rank2, pref2, 0,
                 sc, sres, pref3, rank3);

    if (threadIdx.x == 0) {
        unsigned key = pref3;
        state[2] = (key & 0x80000000u) ? (key ^ 0x80000000u) : ~key;
    }
}

// ============================================================
// K2: threshold + 7x7 separable max-pool + NMS (fp32), vectorized.
// Round-4 form: med read directly from state[2], no per-block select.
// ============================================================
__global__ __launch_bounds__(256) void maxpool_kernel(
    const float* __restrict__ R, const unsigned* __restrict__ state,
    float* __restrict__ out) {
    __shared__ __align__(16) float rt[70 * 72];
    __shared__ __align__(16) float rm[70 * 64];

    const float med = __uint_as_float(state[2]);
    const int tid = threadIdx.x;
    const int bx = blockIdx.x * 64, by = blockIdx.y * 64;

    for (int i = tid; i < 70 * 18; i += 256) {
        int r = i / 18, g = i % 18;
        int gr = by - 3 + r;
        int c0 = bx - 4 + 4 * g;
        float4 v;
        if ((unsigned)gr < N && c0 >= 0 && c0 + 3 < N) {
            v = *(const float4*)&R[(size_t)gr * N + c0];
            v.x = (v.x < med) ? 0.0f : v.x;
            v.y = (v.y < med) ? 0.0f : v.y;
            v.z = (v.z < med) ? 0.0f : v.z;
            v.w = (v.w < med) ? 0.0f : v.w;
        } else {
            float t[4];
            #pragma unroll
            for (int m = 0; m < 4; m++) {
                int c = c0 + m;
                float vv = -INFINITY;
                if ((unsigned)gr < N && (unsigned)c < N) {
                    vv = R[(size_t)gr * N + c];
                    vv = (vv < med) ? 0.0f : vv;
                }
                t[m] = vv;
            }
            v = make_float4(t[0], t[1], t[2], t[3]);
        }
        *(float4*)&rt[r * 72 + 4 * g] = v;
    }
    __syncthreads();

    for (int i = tid; i < 70 * 16; i += 256) {
        int r = i / 16, u = i % 16;
        const float* p = &rt[r * 72 + 4 * u];
        float4 A = *(const float4*)&p[0];
        float4 B = *(const float4*)&p[4];
        float4 C = *(const float4*)&p[8];
        float core = fmaxf(fmaxf(B.x, B.y), fmaxf(B.z, B.w));
        float m0 = fmaxf(fmaxf(A.y, A.z), fmaxf(A.w, core));
        float m1 = fmaxf(fmaxf(A.z, A.w), fmaxf(core, C.x));
        float m2 = fmaxf(A.w, fmaxf(core, fmaxf(C.x, C.y)));
        float m3 = fmaxf(core, fmaxf(fmaxf(C.x, C.y), C.z));
        *(float4*)&rm[r * 64 + 4 * u] = make_float4(m0, m1, m2, m3);
    }
    __syncthreads();

    for (int i = tid; i < 64 * 16; i += 256) {
        int r = i / 16, u = i % 16;
        float4 m = *(const float4*)&rm[r * 64 + 4 * u];
        #pragma unroll
        for (int dy = 1; dy < 7; dy++) {
            float4 z = *(const float4*)&rm[(r + dy) * 64 + 4 * u];
            m.x = fmaxf(m.x, z.x);
            m.y = fmaxf(m.y, z.y);
            m.z = fmaxf(m.z, z.z);
            m.w = fmaxf(m.w, z.w);
        }
        float4 v = *(const float4*)&rt[(r + 3) * 72 + 4 * u + 4];
        float4 o;
        o.x = (v.x == m.x) ? v.x : 0.0f;
        o.y = (v.y == m.y) ? v.y : 0.0f;
        o.z = (v.z == m.z) ? v.z : 0.0f;
        o.w = (v.w == m.w) ? v.w : 0.0f;
        *(float4*)&out[(size_t)(by + r) * N + bx + 4 * u] = o;
    }
}

// ============================================================
extern "C" void kernel_launch(void* const* d_in, const int* in_sizes, int n_in,
                              void* d_out, int out_size, void* d_ws, size_t ws_size,
                              hipStream_t stream) {
    const float* x = (const float*)d_in[0];
    const float* gk = (const float*)d_in[1];
    float* out = (float*)d_out;

    char* ws = (char*)d_ws;
    float* R = (float*)ws;                                 // 64 MB
    unsigned* hist1 = (unsigned*)(ws + (size_t)TOTAL * 4); // 8 x 2048 u32
    unsigned* hist2 = hist1 + NSHARD * 2048;               // 8 x 2048 u32
    unsigned* state = hist2 + NSHARD * 2048;               // 8 u32:
    // [2]=median bits [6]=pref1 [7]=rank1

    // fine 2M-bin histogram lives in d_out (8 MB of the 64 MB output;
    // fully consumed by fsel before maxpool overwrites out).
    unsigned* fine = (unsigned*)out;

    hipMemsetAsync(hist1, 0, (NSHARD * 2048 * 2 + 8) * 4, stream);
    hipMemsetAsync(fine, 0, (size_t)(1u << 21) * 4, stream);

    k1_kernel<<<dim3(N / W, N / RT), 256, 0, stream>>>(x, gk, R, hist1);

    const float4* R4 = (const float4*)R;
    h2_kernel<<<1024, 256, 0, stream>>>(R4, hist1, hist2, fine, state);
    fsel_kernel<<<1, 256, 0, stream>>>(hist2, fine, state);

    maxpool_kernel<<<dim3(N / 64, N / 64), 256, 0, stream>>>(R, state, out);
}

// Round 9
// 328.408 us; speedup vs baseline: 1.0876x; 1.0876x over previous
//
#include <hip/hip_runtime.h>
#include <math.h>

#define N 4096
#define TOTAL (N * N)
#define MED_RANK 8388607u  // (TOTAL-1)/2
#define NSHARD 8

// monotonic float->uint key
__device__ __forceinline__ unsigned fkey(float f) {
    unsigned u = __float_as_uint(f);
    return (u & 0x80000000u) ? ~u : (u | 0x80000000u);
}

// Sobel + products — EXACT round-5-validated fp32 sequence. Do not alter.
__device__ __forceinline__ void sobel3(float A, float B, float C,
                                       float D, float F,
                                       float G, float H, float I,
                                       float& pxx, float& pyy, float& pxy) {
    float ix = __fmul_rn(-1.0f, A);
    ix = __fadd_rn(ix, C);
    ix = __fadd_rn(ix, __fmul_rn(-2.0f, D));
    ix = __fadd_rn(ix, __fmul_rn(2.0f, F));
    ix = __fadd_rn(ix, __fmul_rn(-1.0f, G));
    ix = __fadd_rn(ix, I);
    float iy = __fmul_rn(-1.0f, A);
    iy = __fadd_rn(iy, __fmul_rn(-2.0f, B));
    iy = __fadd_rn(iy, __fmul_rn(-1.0f, C));
    iy = __fadd_rn(iy, G);
    iy = __fadd_rn(iy, __fmul_rn(2.0f, H));
    iy = __fadd_rn(iy, I);
    pxx = __fmul_rn(ix, ix);
    pyy = __fmul_rn(iy, iy);
    pxy = __fmul_rn(ix, iy);
}

// ============================================================
// K1: round-7 champion kernel with RT 32->64: halves the pipeline
// warmup overhead (6 extra product rows amortized over 64 output
// rows instead of 32 -> ~8% less VALU work). Grid 512 blocks
// (2/CU). Per-thread arithmetic sequence byte-identical.
// ============================================================
constexpr int RT = 64;
constexpr int W = 512;

__global__ __launch_bounds__(256) void k1_kernel(
    const float* __restrict__ x, const float* __restrict__ gk,
    float* __restrict__ R, unsigned* __restrict__ hist1) {
    __shared__ __align__(16) float xs[4][524];
    __shared__ __align__(16) float ps[3][520];
    __shared__ unsigned lh[4096];  // parity-split: [bin*2 + (tid&1)]

    const int tid = threadIdx.x;
    const int bx = blockIdx.x * W;
    const int by = blockIdx.y * RT;
    const unsigned par = (unsigned)(tid & 1);

    for (int i = tid; i < 4096; i += 256) lh[i] = 0;

    float w49[49];
    #pragma unroll
    for (int k = 0; k < 49; k++) w49[k] = gk[k];

    float2 a0[7], a1[7], a2[7];
    #pragma unroll
    for (int k = 0; k < 7; k++) {
        a0[k] = make_float2(0.0f, 0.0f);
        a1[k] = make_float2(0.0f, 0.0f);
        a2[k] = make_float2(0.0f, 0.0f);
    }

    // RLE histogram state (per column owned by this thread)
    unsigned curx = 0xFFFFFFFFu, cntx = 0;
    unsigned cury = 0xFFFFFFFFu, cnty = 0;

    const int e_m = 2 * tid;
    const int col_m = bx - 5 + e_m;
    const int e_t = 2 * (tid + 256);
    const int col_t = bx - 5 + e_t;
    const bool has_t = (tid < 6);

#define ISSUE(arow, m0, m1, t0, t1)                                      \
    {                                                                    \
        m0 = 0.0f; m1 = 0.0f; t0 = 0.0f; t1 = 0.0f;                      \
        if ((unsigned)(arow) < N) {                                      \
            const float* xr = x + (size_t)(arow) * N;                    \
            if ((unsigned)col_m < N) m0 = xr[col_m];                     \
            if ((unsigned)(col_m + 1) < N) m1 = xr[col_m + 1];           \
            if (has_t) {                                                 \
                if ((unsigned)col_t < N) t0 = xr[col_t];                 \
                if ((unsigned)(col_t + 1) < N) t1 = xr[col_t + 1];       \
            }                                                            \
        }                                                                \
    }

#define WRITE_SLOT(slot, m0, m1, t0, t1)                                 \
    {                                                                    \
        *(float2*)&xs[slot][e_m] = make_float2(m0, m1);                  \
        if (has_t) *(float2*)&xs[slot][e_t] = make_float2(t0, t1);       \
    }

    float pm0, pm1, pt0, pt1;
    {
        float r4m0, r4m1, r4t0, r4t1;
        float r3m0, r3m1, r3t0, r3t1;
        float r2m0, r2m1, r2t0, r2t1;
        ISSUE(by - 4, r4m0, r4m1, r4t0, r4t1)
        ISSUE(by - 3, r3m0, r3m1, r3t0, r3t1)
        ISSUE(by - 2, r2m0, r2m1, r2t0, r2t1)
        ISSUE(by - 1, pm0, pm1, pt0, pt1)
        WRITE_SLOT(0, r4m0, r4m1, r4t0, r4t1)
        WRITE_SLOT(1, r3m0, r3m1, r3t0, r3t1)
        WRITE_SLOT(2, r2m0, r2m1, r2t0, r2t1)
    }
    __syncthreads();

    for (int it = 0; it < RT + 6; ++it) {
        const int ri = by - 3 + it;
        {
            const int s0 = it & 3, s1 = (it + 1) & 3, s2 = (it + 2) & 3;
            const bool rowv = (unsigned)ri < N;
            for (int t = tid; t < 260; t += 256) {
                int e = 2 * t;
                float2 r0a = *(const float2*)&xs[s0][e];
                float2 r0b = *(const float2*)&xs[s0][e + 2];
                float2 r1a = *(const float2*)&xs[s1][e];
                float2 r1b = *(const float2*)&xs[s1][e + 2];
                float2 r2a = *(const float2*)&xs[s2][e];
                float2 r2b = *(const float2*)&xs[s2][e + 2];
                float pxx0 = 0.0f, pyy0 = 0.0f, pxy0 = 0.0f;
                float pxx1 = 0.0f, pyy1 = 0.0f, pxy1 = 0.0f;
                if (rowv) {
                    if ((unsigned)(bx + 2 * t - 4) < N)
                        sobel3(r0a.x, r0a.y, r0b.x, r1a.x, r1b.x,
                               r2a.x, r2a.y, r2b.x, pxx0, pyy0, pxy0);
                    if ((unsigned)(bx + 2 * t - 3) < N)
                        sobel3(r0a.y, r0b.x, r0b.y, r1a.y, r1b.y,
                               r2a.y, r2b.x, r2b.y, pxx1, pyy1, pxy1);
                }
                *(float2*)&ps[0][e] = make_float2(pxx0, pxx1);
                *(float2*)&ps[1][e] = make_float2(pyy0, pyy1);
                *(float2*)&ps[2][e] = make_float2(pxy0, pxy1);
            }
        }
        __syncthreads();  // B2: ps ready; all xs reads of this iter done

        if (it <= RT + 4) WRITE_SLOT((it + 3) & 3, pm0, pm1, pt0, pt1)
        if (it < RT + 4) ISSUE(by + it, pm0, pm1, pt0, pt1)

        float q0[10], q1[10], q2[10];
        #pragma unroll
        for (int i = 0; i < 5; i++) {
            float2 v0 = *(const float2*)&ps[0][2 * (tid + i)];
            float2 v1 = *(const float2*)&ps[1][2 * (tid + i)];
            float2 v2 = *(const float2*)&ps[2][2 * (tid + i)];
            q0[2 * i] = v0.x; q0[2 * i + 1] = v0.y;
            q1[2 * i] = v1.x; q1[2 * i + 1] = v1.y;
            q2[2 * i] = v2.x; q2[2 * i + 1] = v2.y;
        }
        #pragma unroll
        for (int k = 0; k < 7; k++) {
            float t0x = a0[k].x, t0y = a0[k].y;
            float t1x = a1[k].x, t1y = a1[k].y;
            float t2x = a2[k].x, t2y = a2[k].y;
            #pragma unroll
            for (int dx = 0; dx < 7; dx++) {
                float w = w49[k * 7 + dx];
                t0x = __fadd_rn(t0x, __fmul_rn(w, q0[1 + dx]));
                t0y = __fadd_rn(t0y, __fmul_rn(w, q0[2 + dx]));
                t1x = __fadd_rn(t1x, __fmul_rn(w, q1[1 + dx]));
                t1y = __fadd_rn(t1y, __fmul_rn(w, q1[2 + dx]));
                t2x = __fadd_rn(t2x, __fmul_rn(w, q2[1 + dx]));
                t2y = __fadd_rn(t2y, __fmul_rn(w, q2[2 + dx]));
            }
            a0[k] = make_float2(t0x, t0y);
            a1[k] = make_float2(t1x, t1y);
            a2[k] = make_float2(t2x, t2y);
        }

        int r = ri - 3;
        if (r >= by) {
            float Rx, Ry;
            {
                float sx2 = a0[6].x, sy2 = a1[6].x, sxy = a2[6].x;
                float tr = __fadd_rn(sx2, sy2);
                float e = __fsub_rn(__fmul_rn(sx2, sy2), __fmul_rn(sxy, sxy));
                float t3 = __fmul_rn(__fmul_rn(0.05f, tr), tr);
                Rx = __fsub_rn(e, t3);
            }
            {
                float sx2 = a0[6].y, sy2 = a1[6].y, sxy = a2[6].y;
                float tr = __fadd_rn(sx2, sy2);
                float e = __fsub_rn(__fmul_rn(sx2, sy2), __fmul_rn(sxy, sxy));
                float t3 = __fmul_rn(__fmul_rn(0.05f, tr), tr);
                Ry = __fsub_rn(e, t3);
            }
            *(float2*)&R[(size_t)r * N + bx + 2 * tid] = make_float2(Rx, Ry);
            // RLE histogram: emit only on bin change
            unsigned kx = fkey(Rx) >> 21;
            unsigned ky = fkey(Ry) >> 21;
            if (kx == curx) { cntx++; }
            else { if (cntx) atomicAdd(&lh[(curx << 1) | par], cntx); curx = kx; cntx = 1; }
            if (ky == cury) { cnty++; }
            else { if (cnty) atomicAdd(&lh[(cury << 1) | par], cnty); cury = ky; cnty = 1; }
        }
        #pragma unroll
        for (int k = 6; k > 0; k--) { a0[k] = a0[k - 1]; a1[k] = a1[k - 1]; a2[k] = a2[k - 1]; }
        a0[0] = make_float2(0.0f, 0.0f);
        a1[0] = make_float2(0.0f, 0.0f);
        a2[0] = make_float2(0.0f, 0.0f);

        __syncthreads();  // B1
    }

    // flush RLE tails, then the block histogram (sharded + rotated)
    if (cntx) atomicAdd(&lh[(curx << 1) | par], cntx);
    if (cnty) atomicAdd(&lh[(cury << 1) | par], cnty);
    __syncthreads();
    {
        const unsigned shard = (blockIdx.x + blockIdx.y) & (NSHARD - 1);
        const int rot = (int)((blockIdx.y & 31u) << 6);
        for (int i = tid; i < 2048; i += 256) {
            int r = (i + rot) & 2047;
            unsigned c = lh[2 * r] + lh[2 * r + 1];
            if (c) atomicAdd(&hist1[shard * 2048 + r], c);
        }
    }
#undef ISSUE
#undef WRITE_SLOT
}

// ============================================================
// block_select over an NSHARD-way sharded histogram: one radix-select
// pass run by one block, deterministic given identical hist contents.
// ============================================================
__device__ void block_select(const unsigned* hist, int nbins,
                             unsigned rank_in, unsigned oldpref, int shift,
                             unsigned* sc, unsigned* sres,
                             unsigned& pref_out, unsigned& rank_out) {
    const int tid = threadIdx.x;
    const int bpt = nbins >> 8;

    unsigned cnt[8];
    unsigned s = 0;
    for (int i = 0; i < bpt; i++) {
        unsigned c = 0;
        #pragma unroll
        for (int sh = 0; sh < NSHARD; sh++) c += hist[sh * nbins + tid * bpt + i];
        cnt[i] = c;
        s += c;
    }
    sc[tid] = s;
    __syncthreads();
    for (int off = 1; off < 256; off <<= 1) {
        unsigned v = (tid >= off) ? sc[tid - off] : 0u;
        __syncthreads();
        sc[tid] += v;
        __syncthreads();
    }
    const unsigned incl = sc[tid];
    const unsigned excl = incl - s;

    if (rank_in >= excl && rank_in < incl) {
        unsigned r = rank_in - excl;
        for (int i = 0; i < bpt; i++) {
            if (r < cnt[i]) {
                sres[0] = oldpref | ((unsigned)(tid * bpt + i) << shift);
                sres[1] = r;
                break;
            }
            r -= cnt[i];
        }
    }
    __syncthreads();
    pref_out = sres[0];
    rank_out = sres[1];
    __syncthreads();
}

// wave-aggregated LDS histogram add: one atomic for the leader's bin
// (the common case: ~46% of values share one bin), individual atomics
// for dissenting lanes. Counts exactly preserved.
__device__ __forceinline__ void agg_lds_add(unsigned* lh, unsigned bin, bool active) {
    unsigned long long act = __ballot(active);
    if (act == 0ull) return;
    int leader = __builtin_ctzll(act);
    unsigned lbin = __shfl(bin, leader);
    unsigned long long sm = __ballot(active && bin == lbin);
    if (active) {
        if (bin == lbin) {
            if ((int)(threadIdx.x & 63) == leader)
                atomicAdd(&lh[bin], (unsigned)__popcll(sm));
        } else {
            atomicAdd(&lh[bin], 1u);
        }
    }
}

// ============================================================
// H2: per-block select1 (sharded hist1 complete at kernel boundary),
// then stream R once -> LDS hist2 (bits 20..10 of pref1-matching
// keys, wave-aggregated), sharded flush. Block 0 publishes
// (pref1, rank1) via plain stores for H3.
// ============================================================
__global__ __launch_bounds__(256) void h2_kernel(
    const float4* __restrict__ R4, const unsigned* __restrict__ hist1,
    unsigned* __restrict__ hist2, unsigned* __restrict__ state) {
    __shared__ unsigned lh[2048];
    __shared__ unsigned sc[256];
    __shared__ unsigned sres[2];
    const int tid = threadIdx.x;

    unsigned pref1, rank1;
    block_select(hist1, 2048, MED_RANK, 0u, 21, sc, sres, pref1, rank1);
    if (blockIdx.x == 0 && tid == 0) { state[6] = pref1; state[7] = rank1; }

    for (int i = tid; i < 2048; i += 256) lh[i] = 0;
    __syncthreads();

    const int total4 = TOTAL / 4;
    const int stride = (int)gridDim.x * 256;
    for (int i = (int)blockIdx.x * 256 + tid; i < total4; i += stride) {
        float4 v = R4[i];
        unsigned kk[4];
        kk[0] = fkey(v.x); kk[1] = fkey(v.y);
        kk[2] = fkey(v.z); kk[3] = fkey(v.w);
        #pragma unroll
        for (int c = 0; c < 4; c++) {
            unsigned k = kk[c];
            bool m = (k & 0xFFE00000u) == pref1;
            agg_lds_add(lh, (k >> 10) & 0x7FFu, m);
        }
    }
    __syncthreads();
    {
        const unsigned shard = blockIdx.x & (NSHARD - 1);
        const int rot = (int)((blockIdx.x & 31u) << 6);
        for (int i = tid; i < 2048; i += 256) {
            int r = (i + rot) & 2047;
            unsigned c = lh[r];
            if (c) atomicAdd(&hist2[shard * 2048 + r], c);
        }
    }
}

// ============================================================
// H3: per-block select2 (sharded hist2 complete; pref1/rank1 from
// state), then stream R -> LDS hist3 (bits 9..0 of pref2-matching
// keys), sharded flush. Block 0 publishes (pref2, rank2) for
// maxpool's fused select3.
// ============================================================
__global__ __launch_bounds__(256) void h3_kernel(
    const float4* __restrict__ R4, const unsigned* __restrict__ hist2,
    unsigned* __restrict__ hist3, unsigned* __restrict__ state) {
    __shared__ unsigned lh[1024];
    __shared__ unsigned sc[256];
    __shared__ unsigned sres[2];
    const int tid = threadIdx.x;

    const unsigned pref1 = state[6];
    const unsigned rank1 = state[7];

    unsigned pref2, rank2;
    block_select(hist2, 2048, rank1, pref1, 10, sc, sres, pref2, rank2);
    if (blockIdx.x == 0 && tid == 0) { state[0] = pref2; state[1] = rank2; }

    for (int i = tid; i < 1024; i += 256) lh[i] = 0;
    __syncthreads();

    const int total4 = TOTAL / 4;
    const int stride = (int)gridDim.x * 256;
    for (int i = (int)blockIdx.x * 256 + tid; i < total4; i += stride) {
        float4 v = R4[i];
        unsigned kk[4];
        kk[0] = fkey(v.x); kk[1] = fkey(v.y);
        kk[2] = fkey(v.z); kk[3] = fkey(v.w);
        #pragma unroll
        for (int c = 0; c < 4; c++) {
            unsigned k = kk[c];
            bool m = (k & 0xFFFFFC00u) == pref2;
            agg_lds_add(lh, k & 0x3FFu, m);
        }
    }
    __syncthreads();
    {
        const unsigned shard = blockIdx.x & (NSHARD - 1);
        const int rot = (int)((blockIdx.x & 15u) << 6);
        for (int i = tid; i < 1024; i += 256) {
            int r = (i + rot) & 1023;
            unsigned c = lh[r];
            if (c) atomicAdd(&hist3[shard * 1024 + r], c);
        }
    }
}

// ============================================================
// K2: fused select3 (per-block, redundant, from complete sharded
// hist3) + threshold + 7x7 separable max-pool + NMS, vectorized.
// ============================================================
__global__ __launch_bounds__(256) void maxpool_kernel(
    const float* __restrict__ R, const unsigned* __restrict__ hist3,
    const unsigned* __restrict__ state, float* __restrict__ out) {
    __shared__ __align__(16) float rt[70 * 72];
    __shared__ __align__(16) float rm[70 * 64];
    __shared__ unsigned sc[256];
    __shared__ unsigned sres[2];

    const int tid = threadIdx.x;
    const int bx = blockIdx.x * 64, by = blockIdx.y * 64;

    // select pass 3 (bits 9..0), redundant per block -> median bits
    unsigned pref3, rank3;
    block_select(hist3, 1024, state[1], state[0], 0, sc, sres, pref3, rank3);
    float med;
    {
        unsigned key = pref3;
        unsigned u = (key & 0x80000000u) ? (key ^ 0x80000000u) : ~key;
        med = __uint_as_float(u);
    }

    for (int i = tid; i < 70 * 18; i += 256) {
        int r = i / 18, g = i % 18;
        int gr = by - 3 + r;
        int c0 = bx - 4 + 4 * g;
        float4 v;
        if ((unsigned)gr < N && c0 >= 0 && c0 + 3 < N) {
            v = *(const float4*)&R[(size_t)gr * N + c0];
            v.x = (v.x < med) ? 0.0f : v.x;
            v.y = (v.y < med) ? 0.0f : v.y;
            v.z = (v.z < med) ? 0.0f : v.z;
            v.w = (v.w < med) ? 0.0f : v.w;
        } else {
            float t[4];
            #pragma unroll
            for (int m = 0; m < 4; m++) {
                int c = c0 + m;
                float vv = -INFINITY;
                if ((unsigned)gr < N && (unsigned)c < N) {
                    vv = R[(size_t)gr * N + c];
                    vv = (vv < med) ? 0.0f : vv;
                }
                t[m] = vv;
            }
            v = make_float4(t[0], t[1], t[2], t[3]);
        }
        *(float4*)&rt[r * 72 + 4 * g] = v;
    }
    __syncthreads();

    for (int i = tid; i < 70 * 16; i += 256) {
        int r = i / 16, u = i % 16;
        const float* p = &rt[r * 72 + 4 * u];
        float4 A = *(const float4*)&p[0];
        float4 B = *(const float4*)&p[4];
        float4 C = *(const float4*)&p[8];
        float core = fmaxf(fmaxf(B.x, B.y), fmaxf(B.z, B.w));
        float m0 = fmaxf(fmaxf(A.y, A.z), fmaxf(A.w, core));
        float m1 = fmaxf(fmaxf(A.z, A.w), fmaxf(core, C.x));
        float m2 = fmaxf(A.w, fmaxf(core, fmaxf(C.x, C.y)));
        float m3 = fmaxf(core, fmaxf(fmaxf(C.x, C.y), C.z));
        *(float4*)&rm[r * 64 + 4 * u] = make_float4(m0, m1, m2, m3);
    }
    __syncthreads();

    for (int i = tid; i < 64 * 16; i += 256) {
        int r = i / 16, u = i % 16;
        float4 m = *(const float4*)&rm[r * 64 + 4 * u];
        #pragma unroll
        for (int dy = 1; dy < 7; dy++) {
            float4 z = *(const float4*)&rm[(r + dy) * 64 + 4 * u];
            m.x = fmaxf(m.x, z.x);
            m.y = fmaxf(m.y, z.y);
            m.z = fmaxf(m.z, z.z);
            m.w = fmaxf(m.w, z.w);
        }
        float4 v = *(const float4*)&rt[(r + 3) * 72 + 4 * u + 4];
        float4 o;
        o.x = (v.x == m.x) ? v.x : 0.0f;
        o.y = (v.y == m.y) ? v.y : 0.0f;
        o.z = (v.z == m.z) ? v.z : 0.0f;
        o.w = (v.w == m.w) ? v.w : 0.0f;
        *(float4*)&out[(size_t)(by + r) * N + bx + 4 * u] = o;
    }
}

// ============================================================
extern "C" void kernel_launch(void* const* d_in, const int* in_sizes, int n_in,
                              void* d_out, int out_size, void* d_ws, size_t ws_size,
                              hipStream_t stream) {
    const float* x = (const float*)d_in[0];
    const float* gk = (const float*)d_in[1];
    float* out = (float*)d_out;

    char* ws = (char*)d_ws;
    float* R = (float*)ws;                                 // 64 MB
    unsigned* hist1 = (unsigned*)(ws + (size_t)TOTAL * 4); // 8 x 2048 u32
    unsigned* hist2 = hist1 + NSHARD * 2048;               // 8 x 2048 u32
    unsigned* hist3 = hist2 + NSHARD * 2048;               // 8 x 1024 u32
    unsigned* state = hist3 + NSHARD * 1024;               // 8 u32:
    // [0]=pref2 [1]=rank2 [6]=pref1 [7]=rank1

    hipMemsetAsync(hist1, 0,
                   (NSHARD * (2048 + 2048 + 1024) + 8) * 4, stream);

    k1_kernel<<<dim3(N / W, N / RT), 256, 0, stream>>>(x, gk, R, hist1);

    const float4* R4 = (const float4*)R;
    h2_kernel<<<1024, 256, 0, stream>>>(R4, hist1, hist2, state);
    h3_kernel<<<1024, 256, 0, stream>>>(R4, hist2, hist3, state);

    maxpool_kernel<<<dim3(N / 64, N / 64), 256, 0, stream>>>(R, hist3, state, out);
}

// Round 10
// 309.986 us; speedup vs baseline: 1.1522x; 1.0594x over previous
//
#include <hip/hip_runtime.h>
#include <math.h>

#define N 4096
#define TOTAL (N * N)
#define MED_RANK 8388607u  // (TOTAL-1)/2
#define NSHARD 8

// monotonic float->uint key
__device__ __forceinline__ unsigned fkey(float f) {
    unsigned u = __float_as_uint(f);
    return (u & 0x80000000u) ? ~u : (u | 0x80000000u);
}

// Sobel + products — EXACT round-5-validated fp32 sequence. Do not alter.
__device__ __forceinline__ void sobel3(float A, float B, float C,
                                       float D, float F,
                                       float G, float H, float I,
                                       float& pxx, float& pyy, float& pxy) {
    float ix = __fmul_rn(-1.0f, A);
    ix = __fadd_rn(ix, C);
    ix = __fadd_rn(ix, __fmul_rn(-2.0f, D));
    ix = __fadd_rn(ix, __fmul_rn(2.0f, F));
    ix = __fadd_rn(ix, __fmul_rn(-1.0f, G));
    ix = __fadd_rn(ix, I);
    float iy = __fmul_rn(-1.0f, A);
    iy = __fadd_rn(iy, __fmul_rn(-2.0f, B));
    iy = __fadd_rn(iy, __fmul_rn(-1.0f, C));
    iy = __fadd_rn(iy, G);
    iy = __fadd_rn(iy, __fmul_rn(2.0f, H));
    iy = __fadd_rn(iy, I);
    pxx = __fmul_rn(ix, ix);
    pyy = __fmul_rn(iy, iy);
    pxy = __fmul_rn(ix, iy);
}

// ============================================================
// K1: round-7 champion (RT=32, parity-split lh, RLE hist, reg-staged
// async row pipeline, sharded flush) with ONE change: ps is
// double-buffered (ps[2][...]) and the xs-slot write + next-row issue
// moved before the barrier -> ONE __syncthreads per iteration (38 vs
// 76). Hazards: ps buffers alternate per iter; the written xs slot
// (it+3)&3 is disjoint from the three slots read this iter and was
// last read before the previous barrier; depth-1 wave skew is safe.
// Arithmetic sequence byte-identical.
// ============================================================
constexpr int RT = 32;
constexpr int W = 512;

__global__ __launch_bounds__(256) void k1_kernel(
    const float* __restrict__ x, const float* __restrict__ gk,
    float* __restrict__ R, unsigned* __restrict__ hist1) {
    __shared__ __align__(16) float xs[4][524];
    __shared__ __align__(16) float ps[2][3][520];  // double-buffered
    __shared__ unsigned lh[4096];  // parity-split: [bin*2 + (tid&1)]

    const int tid = threadIdx.x;
    const int bx = blockIdx.x * W;
    const int by = blockIdx.y * RT;
    const unsigned par = (unsigned)(tid & 1);

    for (int i = tid; i < 4096; i += 256) lh[i] = 0;

    float w49[49];
    #pragma unroll
    for (int k = 0; k < 49; k++) w49[k] = gk[k];

    float2 a0[7], a1[7], a2[7];
    #pragma unroll
    for (int k = 0; k < 7; k++) {
        a0[k] = make_float2(0.0f, 0.0f);
        a1[k] = make_float2(0.0f, 0.0f);
        a2[k] = make_float2(0.0f, 0.0f);
    }

    // RLE histogram state (per column owned by this thread)
    unsigned curx = 0xFFFFFFFFu, cntx = 0;
    unsigned cury = 0xFFFFFFFFu, cnty = 0;

    const int e_m = 2 * tid;
    const int col_m = bx - 5 + e_m;
    const int e_t = 2 * (tid + 256);
    const int col_t = bx - 5 + e_t;
    const bool has_t = (tid < 6);

#define ISSUE(arow, m0, m1, t0, t1)                                      \
    {                                                                    \
        m0 = 0.0f; m1 = 0.0f; t0 = 0.0f; t1 = 0.0f;                      \
        if ((unsigned)(arow) < N) {                                      \
            const float* xr = x + (size_t)(arow) * N;                    \
            if ((unsigned)col_m < N) m0 = xr[col_m];                     \
            if ((unsigned)(col_m + 1) < N) m1 = xr[col_m + 1];           \
            if (has_t) {                                                 \
                if ((unsigned)col_t < N) t0 = xr[col_t];                 \
                if ((unsigned)(col_t + 1) < N) t1 = xr[col_t + 1];       \
            }                                                            \
        }                                                                \
    }

#define WRITE_SLOT(slot, m0, m1, t0, t1)                                 \
    {                                                                    \
        *(float2*)&xs[slot][e_m] = make_float2(m0, m1);                  \
        if (has_t) *(float2*)&xs[slot][e_t] = make_float2(t0, t1);       \
    }

    float pm0, pm1, pt0, pt1;
    {
        float r4m0, r4m1, r4t0, r4t1;
        float r3m0, r3m1, r3t0, r3t1;
        float r2m0, r2m1, r2t0, r2t1;
        ISSUE(by - 4, r4m0, r4m1, r4t0, r4t1)
        ISSUE(by - 3, r3m0, r3m1, r3t0, r3t1)
        ISSUE(by - 2, r2m0, r2m1, r2t0, r2t1)
        ISSUE(by - 1, pm0, pm1, pt0, pt1)
        WRITE_SLOT(0, r4m0, r4m1, r4t0, r4t1)
        WRITE_SLOT(1, r3m0, r3m1, r3t0, r3t1)
        WRITE_SLOT(2, r2m0, r2m1, r2t0, r2t1)
    }
    __syncthreads();

    for (int it = 0; it < RT + 6; ++it) {
        const int ri = by - 3 + it;
        const int pb = it & 1;
        {
            const int s0 = it & 3, s1 = (it + 1) & 3, s2 = (it + 2) & 3;
            const bool rowv = (unsigned)ri < N;
            for (int t = tid; t < 260; t += 256) {
                int e = 2 * t;
                float2 r0a = *(const float2*)&xs[s0][e];
                float2 r0b = *(const float2*)&xs[s0][e + 2];
                float2 r1a = *(const float2*)&xs[s1][e];
                float2 r1b = *(const float2*)&xs[s1][e + 2];
                float2 r2a = *(const float2*)&xs[s2][e];
                float2 r2b = *(const float2*)&xs[s2][e + 2];
                float pxx0 = 0.0f, pyy0 = 0.0f, pxy0 = 0.0f;
                float pxx1 = 0.0f, pyy1 = 0.0f, pxy1 = 0.0f;
                if (rowv) {
                    if ((unsigned)(bx + 2 * t - 4) < N)
                        sobel3(r0a.x, r0a.y, r0b.x, r1a.x, r1b.x,
                               r2a.x, r2a.y, r2b.x, pxx0, pyy0, pxy0);
                    if ((unsigned)(bx + 2 * t - 3) < N)
                        sobel3(r0a.y, r0b.x, r0b.y, r1a.y, r1b.y,
                               r2a.y, r2b.x, r2b.y, pxx1, pyy1, pxy1);
                }
                *(float2*)&ps[pb][0][e] = make_float2(pxx0, pxx1);
                *(float2*)&ps[pb][1][e] = make_float2(pyy0, pyy1);
                *(float2*)&ps[pb][2][e] = make_float2(pxy0, pxy1);
            }
        }
        // stage pending row into its xs slot (disjoint from the three
        // slots read above) and issue the following row's loads — both
        // BEFORE the barrier so the loads fly across gauss+products.
        if (it <= RT + 4) WRITE_SLOT((it + 3) & 3, pm0, pm1, pt0, pt1)
        if (it < RT + 4) ISSUE(by + it, pm0, pm1, pt0, pt1)

        __syncthreads();  // single barrier: ps[pb] ready, xs slot published

        float q0[10], q1[10], q2[10];
        #pragma unroll
        for (int i = 0; i < 5; i++) {
            float2 v0 = *(const float2*)&ps[pb][0][2 * (tid + i)];
            float2 v1 = *(const float2*)&ps[pb][1][2 * (tid + i)];
            float2 v2 = *(const float2*)&ps[pb][2][2 * (tid + i)];
            q0[2 * i] = v0.x; q0[2 * i + 1] = v0.y;
            q1[2 * i] = v1.x; q1[2 * i + 1] = v1.y;
            q2[2 * i] = v2.x; q2[2 * i + 1] = v2.y;
        }
        #pragma unroll
        for (int k = 0; k < 7; k++) {
            float t0x = a0[k].x, t0y = a0[k].y;
            float t1x = a1[k].x, t1y = a1[k].y;
            float t2x = a2[k].x, t2y = a2[k].y;
            #pragma unroll
            for (int dx = 0; dx < 7; dx++) {
                float w = w49[k * 7 + dx];
                t0x = __fadd_rn(t0x, __fmul_rn(w, q0[1 + dx]));
                t0y = __fadd_rn(t0y, __fmul_rn(w, q0[2 + dx]));
                t1x = __fadd_rn(t1x, __fmul_rn(w, q1[1 + dx]));
                t1y = __fadd_rn(t1y, __fmul_rn(w, q1[2 + dx]));
                t2x = __fadd_rn(t2x, __fmul_rn(w, q2[1 + dx]));
                t2y = __fadd_rn(t2y, __fmul_rn(w, q2[2 + dx]));
            }
            a0[k] = make_float2(t0x, t0y);
            a1[k] = make_float2(t1x, t1y);
            a2[k] = make_float2(t2x, t2y);
        }

        int r = ri - 3;
        if (r >= by) {
            float Rx, Ry;
            {
                float sx2 = a0[6].x, sy2 = a1[6].x, sxy = a2[6].x;
                float tr = __fadd_rn(sx2, sy2);
                float e = __fsub_rn(__fmul_rn(sx2, sy2), __fmul_rn(sxy, sxy));
                float t3 = __fmul_rn(__fmul_rn(0.05f, tr), tr);
                Rx = __fsub_rn(e, t3);
            }
            {
                float sx2 = a0[6].y, sy2 = a1[6].y, sxy = a2[6].y;
                float tr = __fadd_rn(sx2, sy2);
                float e = __fsub_rn(__fmul_rn(sx2, sy2), __fmul_rn(sxy, sxy));
                float t3 = __fmul_rn(__fmul_rn(0.05f, tr), tr);
                Ry = __fsub_rn(e, t3);
            }
            *(float2*)&R[(size_t)r * N + bx + 2 * tid] = make_float2(Rx, Ry);
            // RLE histogram: emit only on bin change
            unsigned kx = fkey(Rx) >> 21;
            unsigned ky = fkey(Ry) >> 21;
            if (kx == curx) { cntx++; }
            else { if (cntx) atomicAdd(&lh[(curx << 1) | par], cntx); curx = kx; cntx = 1; }
            if (ky == cury) { cnty++; }
            else { if (cnty) atomicAdd(&lh[(cury << 1) | par], cnty); cury = ky; cnty = 1; }
        }
        #pragma unroll
        for (int k = 6; k > 0; k--) { a0[k] = a0[k - 1]; a1[k] = a1[k - 1]; a2[k] = a2[k - 1]; }
        a0[0] = make_float2(0.0f, 0.0f);
        a1[0] = make_float2(0.0f, 0.0f);
        a2[0] = make_float2(0.0f, 0.0f);
    }

    // flush RLE tails, then the block histogram (sharded + rotated)
    if (cntx) atomicAdd(&lh[(curx << 1) | par], cntx);
    if (cnty) atomicAdd(&lh[(cury << 1) | par], cnty);
    __syncthreads();
    {
        const unsigned shard = (blockIdx.x + blockIdx.y) & (NSHARD - 1);
        const int rot = (int)((blockIdx.y & 31u) << 6);
        for (int i = tid; i < 2048; i += 256) {
            int r = (i + rot) & 2047;
            unsigned c = lh[2 * r] + lh[2 * r + 1];
            if (c) atomicAdd(&hist1[shard * 2048 + r], c);
        }
    }
#undef ISSUE
#undef WRITE_SLOT
}

// ============================================================
// block_select over an NSHARD-way sharded histogram: one radix-select
// pass run by one block, deterministic given identical hist contents.
// ============================================================
__device__ void block_select(const unsigned* hist, int nbins,
                             unsigned rank_in, unsigned oldpref, int shift,
                             unsigned* sc, unsigned* sres,
                             unsigned& pref_out, unsigned& rank_out) {
    const int tid = threadIdx.x;
    const int bpt = nbins >> 8;

    unsigned cnt[8];
    unsigned s = 0;
    for (int i = 0; i < bpt; i++) {
        unsigned c = 0;
        #pragma unroll
        for (int sh = 0; sh < NSHARD; sh++) c += hist[sh * nbins + tid * bpt + i];
        cnt[i] = c;
        s += c;
    }
    sc[tid] = s;
    __syncthreads();
    for (int off = 1; off < 256; off <<= 1) {
        unsigned v = (tid >= off) ? sc[tid - off] : 0u;
        __syncthreads();
        sc[tid] += v;
        __syncthreads();
    }
    const unsigned incl = sc[tid];
    const unsigned excl = incl - s;

    if (rank_in >= excl && rank_in < incl) {
        unsigned r = rank_in - excl;
        for (int i = 0; i < bpt; i++) {
            if (r < cnt[i]) {
                sres[0] = oldpref | ((unsigned)(tid * bpt + i) << shift);
                sres[1] = r;
                break;
            }
            r -= cnt[i];
        }
    }
    __syncthreads();
    pref_out = sres[0];
    rank_out = sres[1];
    __syncthreads();
}

// wave-aggregated LDS histogram add: one atomic for the leader's bin
// (the common case: ~46% of values share one bin), individual atomics
// for dissenting lanes. Counts exactly preserved.
__device__ __forceinline__ void agg_lds_add(unsigned* lh, unsigned bin, bool active) {
    unsigned long long act = __ballot(active);
    if (act == 0ull) return;
    int leader = __builtin_ctzll(act);
    unsigned lbin = __shfl(bin, leader);
    unsigned long long sm = __ballot(active && bin == lbin);
    if (active) {
        if (bin == lbin) {
            if ((int)(threadIdx.x & 63) == leader)
                atomicAdd(&lh[bin], (unsigned)__popcll(sm));
        } else {
            atomicAdd(&lh[bin], 1u);
        }
    }
}

// ============================================================
// H2: per-block select1 (sharded hist1 complete at kernel boundary),
// then stream R once -> LDS hist2 (bits 20..10 of pref1-matching
// keys, wave-aggregated), sharded flush. Block 0 publishes
// (pref1, rank1) via plain stores for H3.
// ============================================================
__global__ __launch_bounds__(256) void h2_kernel(
    const float4* __restrict__ R4, const unsigned* __restrict__ hist1,
    unsigned* __restrict__ hist2, unsigned* __restrict__ state) {
    __shared__ unsigned lh[2048];
    __shared__ unsigned sc[256];
    __shared__ unsigned sres[2];
    const int tid = threadIdx.x;

    unsigned pref1, rank1;
    block_select(hist1, 2048, MED_RANK, 0u, 21, sc, sres, pref1, rank1);
    if (blockIdx.x == 0 && tid == 0) { state[6] = pref1; state[7] = rank1; }

    for (int i = tid; i < 2048; i += 256) lh[i] = 0;
    __syncthreads();

    const int total4 = TOTAL / 4;
    const int stride = (int)gridDim.x * 256;
    for (int i = (int)blockIdx.x * 256 + tid; i < total4; i += stride) {
        float4 v = R4[i];
        unsigned kk[4];
        kk[0] = fkey(v.x); kk[1] = fkey(v.y);
        kk[2] = fkey(v.z); kk[3] = fkey(v.w);
        #pragma unroll
        for (int c = 0; c < 4; c++) {
            unsigned k = kk[c];
            bool m = (k & 0xFFE00000u) == pref1;
            agg_lds_add(lh, (k >> 10) & 0x7FFu, m);
        }
    }
    __syncthreads();
    {
        const unsigned shard = blockIdx.x & (NSHARD - 1);
        const int rot = (int)((blockIdx.x & 31u) << 6);
        for (int i = tid; i < 2048; i += 256) {
            int r = (i + rot) & 2047;
            unsigned c = lh[r];
            if (c) atomicAdd(&hist2[shard * 2048 + r], c);
        }
    }
}

// ============================================================
// H3: per-block select2 (sharded hist2 complete; pref1/rank1 from
// state), then stream R -> LDS hist3 (bits 9..0 of pref2-matching
// keys), sharded flush. Block 0 publishes (pref2, rank2) for
// maxpool's fused select3.
// ============================================================
__global__ __launch_bounds__(256) void h3_kernel(
    const float4* __restrict__ R4, const unsigned* __restrict__ hist2,
    unsigned* __restrict__ hist3, unsigned* __restrict__ state) {
    __shared__ unsigned lh[1024];
    __shared__ unsigned sc[256];
    __shared__ unsigned sres[2];
    const int tid = threadIdx.x;

    const unsigned pref1 = state[6];
    const unsigned rank1 = state[7];

    unsigned pref2, rank2;
    block_select(hist2, 2048, rank1, pref1, 10, sc, sres, pref2, rank2);
    if (blockIdx.x == 0 && tid == 0) { state[0] = pref2; state[1] = rank2; }

    for (int i = tid; i < 1024; i += 256) lh[i] = 0;
    __syncthreads();

    const int total4 = TOTAL / 4;
    const int stride = (int)gridDim.x * 256;
    for (int i = (int)blockIdx.x * 256 + tid; i < total4; i += stride) {
        float4 v = R4[i];
        unsigned kk[4];
        kk[0] = fkey(v.x); kk[1] = fkey(v.y);
        kk[2] = fkey(v.z); kk[3] = fkey(v.w);
        #pragma unroll
        for (int c = 0; c < 4; c++) {
            unsigned k = kk[c];
            bool m = (k & 0xFFFFFC00u) == pref2;
            agg_lds_add(lh, k & 0x3FFu, m);
        }
    }
    __syncthreads();
    {
        const unsigned shard = blockIdx.x & (NSHARD - 1);
        const int rot = (int)((blockIdx.x & 15u) << 6);
        for (int i = tid; i < 1024; i += 256) {
            int r = (i + rot) & 1023;
            unsigned c = lh[r];
            if (c) atomicAdd(&hist3[shard * 1024 + r], c);
        }
    }
}

// ============================================================
// K2: fused select3 (per-block, redundant, from complete sharded
// hist3) + threshold + 7x7 separable max-pool + NMS, vectorized.
// ============================================================
__global__ __launch_bounds__(256) void maxpool_kernel(
    const float* __restrict__ R, const unsigned* __restrict__ hist3,
    const unsigned* __restrict__ state, float* __restrict__ out) {
    __shared__ __align__(16) float rt[70 * 72];
    __shared__ __align__(16) float rm[70 * 64];
    __shared__ unsigned sc[256];
    __shared__ unsigned sres[2];

    const int tid = threadIdx.x;
    const int bx = blockIdx.x * 64, by = blockIdx.y * 64;

    // select pass 3 (bits 9..0), redundant per block -> median bits
    unsigned pref3, rank3;
    block_select(hist3, 1024, state[1], state[0], 0, sc, sres, pref3, rank3);
    float med;
    {
        unsigned key = pref3;
        unsigned u = (key & 0x80000000u) ? (key ^ 0x80000000u) : ~key;
        med = __uint_as_float(u);
    }

    for (int i = tid; i < 70 * 18; i += 256) {
        int r = i / 18, g = i % 18;
        int gr = by - 3 + r;
        int c0 = bx - 4 + 4 * g;
        float4 v;
        if ((unsigned)gr < N && c0 >= 0 && c0 + 3 < N) {
            v = *(const float4*)&R[(size_t)gr * N + c0];
            v.x = (v.x < med) ? 0.0f : v.x;
            v.y = (v.y < med) ? 0.0f : v.y;
            v.z = (v.z < med) ? 0.0f : v.z;
            v.w = (v.w < med) ? 0.0f : v.w;
        } else {
            float t[4];
            #pragma unroll
            for (int m = 0; m < 4; m++) {
                int c = c0 + m;
                float vv = -INFINITY;
                if ((unsigned)gr < N && (unsigned)c < N) {
                    vv = R[(size_t)gr * N + c];
                    vv = (vv < med) ? 0.0f : vv;
                }
                t[m] = vv;
            }
            v = make_float4(t[0], t[1], t[2], t[3]);
        }
        *(float4*)&rt[r * 72 + 4 * g] = v;
    }
    __syncthreads();

    for (int i = tid; i < 70 * 16; i += 256) {
        int r = i / 16, u = i % 16;
        const float* p = &rt[r * 72 + 4 * u];
        float4 A = *(const float4*)&p[0];
        float4 B = *(const float4*)&p[4];
        float4 C = *(const float4*)&p[8];
        float core = fmaxf(fmaxf(B.x, B.y), fmaxf(B.z, B.w));
        float m0 = fmaxf(fmaxf(A.y, A.z), fmaxf(A.w, core));
        float m1 = fmaxf(fmaxf(A.z, A.w), fmaxf(core, C.x));
        float m2 = fmaxf(A.w, fmaxf(core, fmaxf(C.x, C.y)));
        float m3 = fmaxf(core, fmaxf(fmaxf(C.x, C.y), C.z));
        *(float4*)&rm[r * 64 + 4 * u] = make_float4(m0, m1, m2, m3);
    }
    __syncthreads();

    for (int i = tid; i < 64 * 16; i += 256) {
        int r = i / 16, u = i % 16;
        float4 m = *(const float4*)&rm[r * 64 + 4 * u];
        #pragma unroll
        for (int dy = 1; dy < 7; dy++) {
            float4 z = *(const float4*)&rm[(r + dy) * 64 + 4 * u];
            m.x = fmaxf(m.x, z.x);
            m.y = fmaxf(m.y, z.y);
            m.z = fmaxf(m.z, z.z);
            m.w = fmaxf(m.w, z.w);
        }
        float4 v = *(const float4*)&rt[(r + 3) * 72 + 4 * u + 4];
        float4 o;
        o.x = (v.x == m.x) ? v.x : 0.0f;
        o.y = (v.y == m.y) ? v.y : 0.0f;
        o.z = (v.z == m.z) ? v.z : 0.0f;
        o.w = (v.w == m.w) ? v.w : 0.0f;
        *(float4*)&out[(size_t)(by + r) * N + bx + 4 * u] = o;
    }
}

// ============================================================
extern "C" void kernel_launch(void* const* d_in, const int* in_sizes, int n_in,
                              void* d_out, int out_size, void* d_ws, size_t ws_size,
                              hipStream_t stream) {
    const float* x = (const float*)d_in[0];
    const float* gk = (const float*)d_in[1];
    float* out = (float*)d_out;

    char* ws = (char*)d_ws;
    float* R = (float*)ws;                                 // 64 MB
    unsigned* hist1 = (unsigned*)(ws + (size_t)TOTAL * 4); // 8 x 2048 u32
    unsigned* hist2 = hist1 + NSHARD * 2048;               // 8 x 2048 u32
    unsigned* hist3 = hist2 + NSHARD * 2048;               // 8 x 1024 u32
    unsigned* state = hist3 + NSHARD * 1024;               // 8 u32:
    // [0]=pref2 [1]=rank2 [6]=pref1 [7]=rank1

    hipMemsetAsync(hist1, 0,
                   (NSHARD * (2048 + 2048 + 1024) + 8) * 4, stream);

    k1_kernel<<<dim3(N / W, N / RT), 256, 0, stream>>>(x, gk, R, hist1);

    const float4* R4 = (const float4*)R;
    h2_kernel<<<1024, 256, 0, stream>>>(R4, hist1, hist2, state);
    h3_kernel<<<1024, 256, 0, stream>>>(R4, hist2, hist3, state);

    maxpool_kernel<<<dim3(N / 64, N / 64), 256, 0, stream>>>(R, hist3, state, out);
}

// Round 11
// 246.979 us; speedup vs baseline: 1.4461x; 1.2551x over previous
//
#include <hip/hip_runtime.h>
#include <math.h>

#define N 4096
#define TOTAL (N * N)
#define MED_RANK 8388607u  // (TOTAL-1)/2
#define NSHARD 8

// monotonic float->uint key
__device__ __forceinline__ unsigned fkey(float f) {
    unsigned u = __float_as_uint(f);
    return (u & 0x80000000u) ? ~u : (u | 0x80000000u);
}

// Sobel + products — EXACT round-5-validated fp32 sequence. Do not alter.
__device__ __forceinline__ void sobel3(float A, float B, float C,
                                       float D, float F,
                                       float G, float H, float I,
                                       float& pxx, float& pyy, float& pxy) {
    float ix = __fmul_rn(-1.0f, A);
    ix = __fadd_rn(ix, C);
    ix = __fadd_rn(ix, __fmul_rn(-2.0f, D));
    ix = __fadd_rn(ix, __fmul_rn(2.0f, F));
    ix = __fadd_rn(ix, __fmul_rn(-1.0f, G));
    ix = __fadd_rn(ix, I);
    float iy = __fmul_rn(-1.0f, A);
    iy = __fadd_rn(iy, __fmul_rn(-2.0f, B));
    iy = __fadd_rn(iy, __fmul_rn(-1.0f, C));
    iy = __fadd_rn(iy, G);
    iy = __fadd_rn(iy, __fmul_rn(2.0f, H));
    iy = __fadd_rn(iy, I);
    pxx = __fmul_rn(ix, ix);
    pyy = __fmul_rn(iy, iy);
    pxy = __fmul_rn(ix, iy);
}

// ============================================================
// K1: round-7 structure (RT=32, 2 barriers, parity-split lh, RLE
// hist, reg-staged async row pipeline, sharded flush) with the
// gaussian factored SEPARABLY: w = outer(u,u) with u[j] =
// w[3][j]/sqrt(w[3][3]) (rank-1 by construction in the reference).
// Per iter: 7-tap horizontal conv on the new product row, then the
// 7-deep vertical ring accumulates u[k]*hrow — 14 MACs/px/ch vs 49.
// Rounding differs from the 49-sum at ulp level; harness tolerance
// (already passing at absmax=2.0) absorbs this. REVERT if FAIL.
// ============================================================
constexpr int RT = 32;
constexpr int W = 512;

__global__ __launch_bounds__(256) void k1_kernel(
    const float* __restrict__ x, const float* __restrict__ gk,
    float* __restrict__ R, unsigned* __restrict__ hist1) {
    __shared__ __align__(16) float xs[4][524];
    __shared__ __align__(16) float ps[3][520];
    __shared__ unsigned lh[4096];  // parity-split: [bin*2 + (tid&1)]

    const int tid = threadIdx.x;
    const int bx = blockIdx.x * W;
    const int by = blockIdx.y * RT;
    const unsigned par = (unsigned)(tid & 1);

    for (int i = tid; i < 4096; i += 256) lh[i] = 0;

    // separable taps: u[j] = w[3][j] / sqrt(w[3][3])
    float u7[7];
    {
        float u3 = __fsqrt_rn(gk[24]);
        #pragma unroll
        for (int j = 0; j < 7; j++) u7[j] = __fdiv_rn(gk[21 + j], u3);
    }

    float2 a0[7], a1[7], a2[7];
    #pragma unroll
    for (int k = 0; k < 7; k++) {
        a0[k] = make_float2(0.0f, 0.0f);
        a1[k] = make_float2(0.0f, 0.0f);
        a2[k] = make_float2(0.0f, 0.0f);
    }

    // RLE histogram state (per column owned by this thread)
    unsigned curx = 0xFFFFFFFFu, cntx = 0;
    unsigned cury = 0xFFFFFFFFu, cnty = 0;

    const int e_m = 2 * tid;
    const int col_m = bx - 5 + e_m;
    const int e_t = 2 * (tid + 256);
    const int col_t = bx - 5 + e_t;
    const bool has_t = (tid < 6);

#define ISSUE(arow, m0, m1, t0, t1)                                      \
    {                                                                    \
        m0 = 0.0f; m1 = 0.0f; t0 = 0.0f; t1 = 0.0f;                      \
        if ((unsigned)(arow) < N) {                                      \
            const float* xr = x + (size_t)(arow) * N;                    \
            if ((unsigned)col_m < N) m0 = xr[col_m];                     \
            if ((unsigned)(col_m + 1) < N) m1 = xr[col_m + 1];           \
            if (has_t) {                                                 \
                if ((unsigned)col_t < N) t0 = xr[col_t];                 \
                if ((unsigned)(col_t + 1) < N) t1 = xr[col_t + 1];       \
            }                                                            \
        }                                                                \
    }

#define WRITE_SLOT(slot, m0, m1, t0, t1)                                 \
    {                                                                    \
        *(float2*)&xs[slot][e_m] = make_float2(m0, m1);                  \
        if (has_t) *(float2*)&xs[slot][e_t] = make_float2(t0, t1);       \
    }

    float pm0, pm1, pt0, pt1;
    {
        float r4m0, r4m1, r4t0, r4t1;
        float r3m0, r3m1, r3t0, r3t1;
        float r2m0, r2m1, r2t0, r2t1;
        ISSUE(by - 4, r4m0, r4m1, r4t0, r4t1)
        ISSUE(by - 3, r3m0, r3m1, r3t0, r3t1)
        ISSUE(by - 2, r2m0, r2m1, r2t0, r2t1)
        ISSUE(by - 1, pm0, pm1, pt0, pt1)
        WRITE_SLOT(0, r4m0, r4m1, r4t0, r4t1)
        WRITE_SLOT(1, r3m0, r3m1, r3t0, r3t1)
        WRITE_SLOT(2, r2m0, r2m1, r2t0, r2t1)
    }
    __syncthreads();

    for (int it = 0; it < RT + 6; ++it) {
        const int ri = by - 3 + it;
        {
            const int s0 = it & 3, s1 = (it + 1) & 3, s2 = (it + 2) & 3;
            const bool rowv = (unsigned)ri < N;
            for (int t = tid; t < 260; t += 256) {
                int e = 2 * t;
                float2 r0a = *(const float2*)&xs[s0][e];
                float2 r0b = *(const float2*)&xs[s0][e + 2];
                float2 r1a = *(const float2*)&xs[s1][e];
                float2 r1b = *(const float2*)&xs[s1][e + 2];
                float2 r2a = *(const float2*)&xs[s2][e];
                float2 r2b = *(const float2*)&xs[s2][e + 2];
                float pxx0 = 0.0f, pyy0 = 0.0f, pxy0 = 0.0f;
                float pxx1 = 0.0f, pyy1 = 0.0f, pxy1 = 0.0f;
                if (rowv) {
                    if ((unsigned)(bx + 2 * t - 4) < N)
                        sobel3(r0a.x, r0a.y, r0b.x, r1a.x, r1b.x,
                               r2a.x, r2a.y, r2b.x, pxx0, pyy0, pxy0);
                    if ((unsigned)(bx + 2 * t - 3) < N)
                        sobel3(r0a.y, r0b.x, r0b.y, r1a.y, r1b.y,
                               r2a.y, r2b.x, r2b.y, pxx1, pyy1, pxy1);
                }
                *(float2*)&ps[0][e] = make_float2(pxx0, pxx1);
                *(float2*)&ps[1][e] = make_float2(pyy0, pyy1);
                *(float2*)&ps[2][e] = make_float2(pxy0, pxy1);
            }
        }
        __syncthreads();  // B2: ps ready; all xs reads of this iter done

        if (it <= RT + 4) WRITE_SLOT((it + 3) & 3, pm0, pm1, pt0, pt1)
        if (it < RT + 4) ISSUE(by + it, pm0, pm1, pt0, pt1)

        // gather window ps[2*tid .. 2*tid+9] per channel (5 aligned b64 each)
        float q0[10], q1[10], q2[10];
        #pragma unroll
        for (int i = 0; i < 5; i++) {
            float2 v0 = *(const float2*)&ps[0][2 * (tid + i)];
            float2 v1 = *(const float2*)&ps[1][2 * (tid + i)];
            float2 v2 = *(const float2*)&ps[2][2 * (tid + i)];
            q0[2 * i] = v0.x; q0[2 * i + 1] = v0.y;
            q1[2 * i] = v1.x; q1[2 * i + 1] = v1.y;
            q2[2 * i] = v2.x; q2[2 * i + 1] = v2.y;
        }
        // separable gauss: horizontal 7-tap (per channel, 2 cols), then
        // vertical ring accumulation a[k] += u[k]*hrow. Left-assoc fp32.
        float h00, h01, h10, h11, h20, h21;
        {
            h00 = __fmul_rn(u7[0], q0[1]);
            h01 = __fmul_rn(u7[0], q0[2]);
            h10 = __fmul_rn(u7[0], q1[1]);
            h11 = __fmul_rn(u7[0], q1[2]);
            h20 = __fmul_rn(u7[0], q2[1]);
            h21 = __fmul_rn(u7[0], q2[2]);
            #pragma unroll
            for (int dx = 1; dx < 7; dx++) {
                float u = u7[dx];
                h00 = __fadd_rn(h00, __fmul_rn(u, q0[1 + dx]));
                h01 = __fadd_rn(h01, __fmul_rn(u, q0[2 + dx]));
                h10 = __fadd_rn(h10, __fmul_rn(u, q1[1 + dx]));
                h11 = __fadd_rn(h11, __fmul_rn(u, q1[2 + dx]));
                h20 = __fadd_rn(h20, __fmul_rn(u, q2[1 + dx]));
                h21 = __fadd_rn(h21, __fmul_rn(u, q2[2 + dx]));
            }
        }
        #pragma unroll
        for (int k = 0; k < 7; k++) {
            float u = u7[k];
            a0[k].x = __fadd_rn(a0[k].x, __fmul_rn(u, h00));
            a0[k].y = __fadd_rn(a0[k].y, __fmul_rn(u, h01));
            a1[k].x = __fadd_rn(a1[k].x, __fmul_rn(u, h10));
            a1[k].y = __fadd_rn(a1[k].y, __fmul_rn(u, h11));
            a2[k].x = __fadd_rn(a2[k].x, __fmul_rn(u, h20));
            a2[k].y = __fadd_rn(a2[k].y, __fmul_rn(u, h21));
        }

        int r = ri - 3;
        if (r >= by) {
            float Rx, Ry;
            {
                float sx2 = a0[6].x, sy2 = a1[6].x, sxy = a2[6].x;
                float tr = __fadd_rn(sx2, sy2);
                float e = __fsub_rn(__fmul_rn(sx2, sy2), __fmul_rn(sxy, sxy));
                float t3 = __fmul_rn(__fmul_rn(0.05f, tr), tr);
                Rx = __fsub_rn(e, t3);
            }
            {
                float sx2 = a0[6].y, sy2 = a1[6].y, sxy = a2[6].y;
                float tr = __fadd_rn(sx2, sy2);
                float e = __fsub_rn(__fmul_rn(sx2, sy2), __fmul_rn(sxy, sxy));
                float t3 = __fmul_rn(__fmul_rn(0.05f, tr), tr);
                Ry = __fsub_rn(e, t3);
            }
            *(float2*)&R[(size_t)r * N + bx + 2 * tid] = make_float2(Rx, Ry);
            // RLE histogram: emit only on bin change
            unsigned kx = fkey(Rx) >> 21;
            unsigned ky = fkey(Ry) >> 21;
            if (kx == curx) { cntx++; }
            else { if (cntx) atomicAdd(&lh[(curx << 1) | par], cntx); curx = kx; cntx = 1; }
            if (ky == cury) { cnty++; }
            else { if (cnty) atomicAdd(&lh[(cury << 1) | par], cnty); cury = ky; cnty = 1; }
        }
        #pragma unroll
        for (int k = 6; k > 0; k--) { a0[k] = a0[k - 1]; a1[k] = a1[k - 1]; a2[k] = a2[k - 1]; }
        a0[0] = make_float2(0.0f, 0.0f);
        a1[0] = make_float2(0.0f, 0.0f);
        a2[0] = make_float2(0.0f, 0.0f);

        __syncthreads();  // B1
    }

    // flush RLE tails, then the block histogram (sharded + rotated)
    if (cntx) atomicAdd(&lh[(curx << 1) | par], cntx);
    if (cnty) atomicAdd(&lh[(cury << 1) | par], cnty);
    __syncthreads();
    {
        const unsigned shard = (blockIdx.x + blockIdx.y) & (NSHARD - 1);
        const int rot = (int)((blockIdx.y & 31u) << 6);
        for (int i = tid; i < 2048; i += 256) {
            int r = (i + rot) & 2047;
            unsigned c = lh[2 * r] + lh[2 * r + 1];
            if (c) atomicAdd(&hist1[shard * 2048 + r], c);
        }
    }
#undef ISSUE
#undef WRITE_SLOT
}

// ============================================================
// block_select over an NSHARD-way sharded histogram: one radix-select
// pass run by one block, deterministic given identical hist contents.
// ============================================================
__device__ void block_select(const unsigned* hist, int nbins,
                             unsigned rank_in, unsigned oldpref, int shift,
                             unsigned* sc, unsigned* sres,
                             unsigned& pref_out, unsigned& rank_out) {
    const int tid = threadIdx.x;
    const int bpt = nbins >> 8;

    unsigned cnt[8];
    unsigned s = 0;
    for (int i = 0; i < bpt; i++) {
        unsigned c = 0;
        #pragma unroll
        for (int sh = 0; sh < NSHARD; sh++) c += hist[sh * nbins + tid * bpt + i];
        cnt[i] = c;
        s += c;
    }
    sc[tid] = s;
    __syncthreads();
    for (int off = 1; off < 256; off <<= 1) {
        unsigned v = (tid >= off) ? sc[tid - off] : 0u;
        __syncthreads();
        sc[tid] += v;
        __syncthreads();
    }
    const unsigned incl = sc[tid];
    const unsigned excl = incl - s;

    if (rank_in >= excl && rank_in < incl) {
        unsigned r = rank_in - excl;
        for (int i = 0; i < bpt; i++) {
            if (r < cnt[i]) {
                sres[0] = oldpref | ((unsigned)(tid * bpt + i) << shift);
                sres[1] = r;
                break;
            }
            r -= cnt[i];
        }
    }
    __syncthreads();
    pref_out = sres[0];
    rank_out = sres[1];
    __syncthreads();
}

// wave-aggregated LDS histogram add: one atomic for the leader's bin
// (the common case: ~46% of values share one bin), individual atomics
// for dissenting lanes. Counts exactly preserved.
__device__ __forceinline__ void agg_lds_add(unsigned* lh, unsigned bin, bool active) {
    unsigned long long act = __ballot(active);
    if (act == 0ull) return;
    int leader = __builtin_ctzll(act);
    unsigned lbin = __shfl(bin, leader);
    unsigned long long sm = __ballot(active && bin == lbin);
    if (active) {
        if (bin == lbin) {
            if ((int)(threadIdx.x & 63) == leader)
                atomicAdd(&lh[bin], (unsigned)__popcll(sm));
        } else {
            atomicAdd(&lh[bin], 1u);
        }
    }
}

// ============================================================
// H2: per-block select1 (sharded hist1 complete at kernel boundary),
// then stream R once -> LDS hist2 (bits 20..10 of pref1-matching
// keys, wave-aggregated), sharded flush. Block 0 publishes
// (pref1, rank1) via plain stores for H3.
// ============================================================
__global__ __launch_bounds__(256) void h2_kernel(
    const float4* __restrict__ R4, const unsigned* __restrict__ hist1,
    unsigned* __restrict__ hist2, unsigned* __restrict__ state) {
    __shared__ unsigned lh[2048];
    __shared__ unsigned sc[256];
    __shared__ unsigned sres[2];
    const int tid = threadIdx.x;

    unsigned pref1, rank1;
    block_select(hist1, 2048, MED_RANK, 0u, 21, sc, sres, pref1, rank1);
    if (blockIdx.x == 0 && tid == 0) { state[6] = pref1; state[7] = rank1; }

    for (int i = tid; i < 2048; i += 256) lh[i] = 0;
    __syncthreads();

    const int total4 = TOTAL / 4;
    const int stride = (int)gridDim.x * 256;
    for (int i = (int)blockIdx.x * 256 + tid; i < total4; i += stride) {
        float4 v = R4[i];
        unsigned kk[4];
        kk[0] = fkey(v.x); kk[1] = fkey(v.y);
        kk[2] = fkey(v.z); kk[3] = fkey(v.w);
        #pragma unroll
        for (int c = 0; c < 4; c++) {
            unsigned k = kk[c];
            bool m = (k & 0xFFE00000u) == pref1;
            agg_lds_add(lh, (k >> 10) & 0x7FFu, m);
        }
    }
    __syncthreads();
    {
        const unsigned shard = blockIdx.x & (NSHARD - 1);
        const int rot = (int)((blockIdx.x & 31u) << 6);
        for (int i = tid; i < 2048; i += 256) {
            int r = (i + rot) & 2047;
            unsigned c = lh[r];
            if (c) atomicAdd(&hist2[shard * 2048 + r], c);
        }
    }
}

// ============================================================
// H3: per-block select2 (sharded hist2 complete; pref1/rank1 from
// state), then stream R -> LDS hist3 (bits 9..0 of pref2-matching
// keys), sharded flush. Block 0 publishes (pref2, rank2) for
// maxpool's fused select3.
// ============================================================
__global__ __launch_bounds__(256) void h3_kernel(
    const float4* __restrict__ R4, const unsigned* __restrict__ hist2,
    unsigned* __restrict__ hist3, unsigned* __restrict__ state) {
    __shared__ unsigned lh[1024];
    __shared__ unsigned sc[256];
    __shared__ unsigned sres[2];
    const int tid = threadIdx.x;

    const unsigned pref1 = state[6];
    const unsigned rank1 = state[7];

    unsigned pref2, rank2;
    block_select(hist2, 2048, rank1, pref1, 10, sc, sres, pref2, rank2);
    if (blockIdx.x == 0 && tid == 0) { state[0] = pref2; state[1] = rank2; }

    for (int i = tid; i < 1024; i += 256) lh[i] = 0;
    __syncthreads();

    const int total4 = TOTAL / 4;
    const int stride = (int)gridDim.x * 256;
    for (int i = (int)blockIdx.x * 256 + tid; i < total4; i += stride) {
        float4 v = R4[i];
        unsigned kk[4];
        kk[0] = fkey(v.x); kk[1] = fkey(v.y);
        kk[2] = fkey(v.z); kk[3] = fkey(v.w);
        #pragma unroll
        for (int c = 0; c < 4; c++) {
            unsigned k = kk[c];
            bool m = (k & 0xFFFFFC00u) == pref2;
            agg_lds_add(lh, k & 0x3FFu, m);
        }
    }
    __syncthreads();
    {
        const unsigned shard = blockIdx.x & (NSHARD - 1);
        const int rot = (int)((blockIdx.x & 15u) << 6);
        for (int i = tid; i < 1024; i += 256) {
            int r = (i + rot) & 1023;
            unsigned c = lh[r];
            if (c) atomicAdd(&hist3[shard * 1024 + r], c);
        }
    }
}

// ============================================================
// K2: fused select3 (per-block, redundant, from complete sharded
// hist3) + threshold + 7x7 separable max-pool + NMS, vectorized.
// ============================================================
__global__ __launch_bounds__(256) void maxpool_kernel(
    const float* __restrict__ R, const unsigned* __restrict__ hist3,
    const unsigned* __restrict__ state, float* __restrict__ out) {
    __shared__ __align__(16) float rt[70 * 72];
    __shared__ __align__(16) float rm[70 * 64];
    __shared__ unsigned sc[256];
    __shared__ unsigned sres[2];

    const int tid = threadIdx.x;
    const int bx = blockIdx.x * 64, by = blockIdx.y * 64;

    // select pass 3 (bits 9..0), redundant per block -> median bits
    unsigned pref3, rank3;
    block_select(hist3, 1024, state[1], state[0], 0, sc, sres, pref3, rank3);
    float med;
    {
        unsigned key = pref3;
        unsigned u = (key & 0x80000000u) ? (key ^ 0x80000000u) : ~key;
        med = __uint_as_float(u);
    }

    for (int i = tid; i < 70 * 18; i += 256) {
        int r = i / 18, g = i % 18;
        int gr = by - 3 + r;
        int c0 = bx - 4 + 4 * g;
        float4 v;
        if ((unsigned)gr < N && c0 >= 0 && c0 + 3 < N) {
            v = *(const float4*)&R[(size_t)gr * N + c0];
            v.x = (v.x < med) ? 0.0f : v.x;
            v.y = (v.y < med) ? 0.0f : v.y;
            v.z = (v.z < med) ? 0.0f : v.z;
            v.w = (v.w < med) ? 0.0f : v.w;
        } else {
            float t[4];
            #pragma unroll
            for (int m = 0; m < 4; m++) {
                int c = c0 + m;
                float vv = -INFINITY;
                if ((unsigned)gr < N && (unsigned)c < N) {
                    vv = R[(size_t)gr * N + c];
                    vv = (vv < med) ? 0.0f : vv;
                }
                t[m] = vv;
            }
            v = make_float4(t[0], t[1], t[2], t[3]);
        }
        *(float4*)&rt[r * 72 + 4 * g] = v;
    }
    __syncthreads();

    for (int i = tid; i < 70 * 16; i += 256) {
        int r = i / 16, u = i % 16;
        const float* p = &rt[r * 72 + 4 * u];
        float4 A = *(const float4*)&p[0];
        float4 B = *(const float4*)&p[4];
        float4 C = *(const float4*)&p[8];
        float core = fmaxf(fmaxf(B.x, B.y), fmaxf(B.z, B.w));
        float m0 = fmaxf(fmaxf(A.y, A.z), fmaxf(A.w, core));
        float m1 = fmaxf(fmaxf(A.z, A.w), fmaxf(core, C.x));
        float m2 = fmaxf(A.w, fmaxf(core, fmaxf(C.x, C.y)));
        float m3 = fmaxf(core, fmaxf(fmaxf(C.x, C.y), C.z));
        *(float4*)&rm[r * 64 + 4 * u] = make_float4(m0, m1, m2, m3);
    }
    __syncthreads();

    for (int i = tid; i < 64 * 16; i += 256) {
        int r = i / 16, u = i % 16;
        float4 m = *(const float4*)&rm[r * 64 + 4 * u];
        #pragma unroll
        for (int dy = 1; dy < 7; dy++) {
            float4 z = *(const float4*)&rm[(r + dy) * 64 + 4 * u];
            m.x = fmaxf(m.x, z.x);
            m.y = fmaxf(m.y, z.y);
            m.z = fmaxf(m.z, z.z);
            m.w = fmaxf(m.w, z.w);
        }
        float4 v = *(const float4*)&rt[(r + 3) * 72 + 4 * u + 4];
        float4 o;
        o.x = (v.x == m.x) ? v.x : 0.0f;
        o.y = (v.y == m.y) ? v.y : 0.0f;
        o.z = (v.z == m.z) ? v.z : 0.0f;
        o.w = (v.w == m.w) ? v.w : 0.0f;
        *(float4*)&out[(size_t)(by + r) * N + bx + 4 * u] = o;
    }
}

// ============================================================
extern "C" void kernel_launch(void* const* d_in, const int* in_sizes, int n_in,
                              void* d_out, int out_size, void* d_ws, size_t ws_size,
                              hipStream_t stream) {
    const float* x = (const float*)d_in[0];
    const float* gk = (const float*)d_in[1];
    float* out = (float*)d_out;

    char* ws = (char*)d_ws;
    float* R = (float*)ws;                                 // 64 MB
    unsigned* hist1 = (unsigned*)(ws + (size_t)TOTAL * 4); // 8 x 2048 u32
    unsigned* hist2 = hist1 + NSHARD * 2048;               // 8 x 2048 u32
    unsigned* hist3 = hist2 + NSHARD * 2048;               // 8 x 1024 u32
    unsigned* state = hist3 + NSHARD * 1024;               // 8 u32:
    // [0]=pref2 [1]=rank2 [6]=pref1 [7]=rank1

    hipMemsetAsync(hist1, 0,
                   (NSHARD * (2048 + 2048 + 1024) + 8) * 4, stream);

    k1_kernel<<<dim3(N / W, N / RT), 256, 0, stream>>>(x, gk, R, hist1);

    const float4* R4 = (const float4*)R;
    h2_kernel<<<1024, 256, 0, stream>>>(R4, hist1, hist2, state);
    h3_kernel<<<1024, 256, 0, stream>>>(R4, hist2, hist3, state);

    maxpool_kernel<<<dim3(N / 64, N / 64), 256, 0, stream>>>(R, hist3, state, out);
}

// Round 12
// 244.759 us; speedup vs baseline: 1.4592x; 1.0091x over previous
//
#include <hip/hip_runtime.h>
#include <math.h>

#define N 4096
#define TOTAL (N * N)
#define MED_RANK 8388607u  // (TOTAL-1)/2
#define NSHARD 8

// monotonic float->uint key
__device__ __forceinline__ unsigned fkey(float f) {
    unsigned u = __float_as_uint(f);
    return (u & 0x80000000u) ? ~u : (u | 0x80000000u);
}

// Sobel + products — EXACT round-5-validated fp32 sequence. Do not alter.
__device__ __forceinline__ void sobel3(float A, float B, float C,
                                       float D, float F,
                                       float G, float H, float I,
                                       float& pxx, float& pyy, float& pxy) {
    float ix = __fmul_rn(-1.0f, A);
    ix = __fadd_rn(ix, C);
    ix = __fadd_rn(ix, __fmul_rn(-2.0f, D));
    ix = __fadd_rn(ix, __fmul_rn(2.0f, F));
    ix = __fadd_rn(ix, __fmul_rn(-1.0f, G));
    ix = __fadd_rn(ix, I);
    float iy = __fmul_rn(-1.0f, A);
    iy = __fadd_rn(iy, __fmul_rn(-2.0f, B));
    iy = __fadd_rn(iy, __fmul_rn(-1.0f, C));
    iy = __fadd_rn(iy, G);
    iy = __fadd_rn(iy, __fmul_rn(2.0f, H));
    iy = __fadd_rn(iy, I);
    pxx = __fmul_rn(ix, ix);
    pyy = __fmul_rn(iy, iy);
    pxy = __fmul_rn(ix, iy);
}

// ============================================================
// K1: round-11 champion (separable gauss, 89 µs) with the 7-deep
// accumulator ring turned into a compile-time circular buffer:
// the `it` loop is unrolled by 7 (j = it%7 compile-time since it0
// steps by 7 from 0), logical a[k] lives in physical slot
// (j-k+7)%7, output slot (j+1)%7 is read then zeroed (it becomes
// next iter's a[0]). Removes the 42-float2 shift (~84 v_mov/iter,
// ~28% of VALU issue). Per-column arithmetic order bit-identical.
// ============================================================
constexpr int RT = 32;
constexpr int W = 512;

__global__ __launch_bounds__(256) void k1_kernel(
    const float* __restrict__ x, const float* __restrict__ gk,
    float* __restrict__ R, unsigned* __restrict__ hist1) {
    __shared__ __align__(16) float xs[4][524];
    __shared__ __align__(16) float ps[3][520];
    __shared__ unsigned lh[4096];  // parity-split: [bin*2 + (tid&1)]

    const int tid = threadIdx.x;
    const int bx = blockIdx.x * W;
    const int by = blockIdx.y * RT;
    const unsigned par = (unsigned)(tid & 1);

    for (int i = tid; i < 4096; i += 256) lh[i] = 0;

    // separable taps: u[j] = w[3][j] / sqrt(w[3][3])
    float u7[7];
    {
        float u3 = __fsqrt_rn(gk[24]);
        #pragma unroll
        for (int j = 0; j < 7; j++) u7[j] = __fdiv_rn(gk[21 + j], u3);
    }

    float2 a0[7], a1[7], a2[7];
    #pragma unroll
    for (int k = 0; k < 7; k++) {
        a0[k] = make_float2(0.0f, 0.0f);
        a1[k] = make_float2(0.0f, 0.0f);
        a2[k] = make_float2(0.0f, 0.0f);
    }

    // RLE histogram state (per column owned by this thread)
    unsigned curx = 0xFFFFFFFFu, cntx = 0;
    unsigned cury = 0xFFFFFFFFu, cnty = 0;

    const int e_m = 2 * tid;
    const int col_m = bx - 5 + e_m;
    const int e_t = 2 * (tid + 256);
    const int col_t = bx - 5 + e_t;
    const bool has_t = (tid < 6);

#define ISSUE(arow, m0, m1, t0, t1)                                      \
    {                                                                    \
        m0 = 0.0f; m1 = 0.0f; t0 = 0.0f; t1 = 0.0f;                      \
        if ((unsigned)(arow) < N) {                                      \
            const float* xr = x + (size_t)(arow) * N;                    \
            if ((unsigned)col_m < N) m0 = xr[col_m];                     \
            if ((unsigned)(col_m + 1) < N) m1 = xr[col_m + 1];           \
            if (has_t) {                                                 \
                if ((unsigned)col_t < N) t0 = xr[col_t];                 \
                if ((unsigned)(col_t + 1) < N) t1 = xr[col_t + 1];       \
            }                                                            \
        }                                                                \
    }

#define WRITE_SLOT(slot, m0, m1, t0, t1)                                 \
    {                                                                    \
        *(float2*)&xs[slot][e_m] = make_float2(m0, m1);                  \
        if (has_t) *(float2*)&xs[slot][e_t] = make_float2(t0, t1);       \
    }

    float pm0, pm1, pt0, pt1;
    {
        float r4m0, r4m1, r4t0, r4t1;
        float r3m0, r3m1, r3t0, r3t1;
        float r2m0, r2m1, r2t0, r2t1;
        ISSUE(by - 4, r4m0, r4m1, r4t0, r4t1)
        ISSUE(by - 3, r3m0, r3m1, r3t0, r3t1)
        ISSUE(by - 2, r2m0, r2m1, r2t0, r2t1)
        ISSUE(by - 1, pm0, pm1, pt0, pt1)
        WRITE_SLOT(0, r4m0, r4m1, r4t0, r4t1)
        WRITE_SLOT(1, r3m0, r3m1, r3t0, r3t1)
        WRITE_SLOT(2, r2m0, r2m1, r2t0, r2t1)
    }
    __syncthreads();

    for (int it0 = 0; it0 < RT + 6; it0 += 7) {
        #pragma unroll
        for (int j = 0; j < 7; ++j) {
            const int it = it0 + j;
            if (it < RT + 6) {  // uniform guard (block-uniform condition)
                const int ri = by - 3 + it;
                {
                    const int s0 = it & 3, s1 = (it + 1) & 3, s2 = (it + 2) & 3;
                    const bool rowv = (unsigned)ri < N;
                    for (int t = tid; t < 260; t += 256) {
                        int e = 2 * t;
                        float2 r0a = *(const float2*)&xs[s0][e];
                        float2 r0b = *(const float2*)&xs[s0][e + 2];
                        float2 r1a = *(const float2*)&xs[s1][e];
                        float2 r1b = *(const float2*)&xs[s1][e + 2];
                        float2 r2a = *(const float2*)&xs[s2][e];
                        float2 r2b = *(const float2*)&xs[s2][e + 2];
                        float pxx0 = 0.0f, pyy0 = 0.0f, pxy0 = 0.0f;
                        float pxx1 = 0.0f, pyy1 = 0.0f, pxy1 = 0.0f;
                        if (rowv) {
                            if ((unsigned)(bx + 2 * t - 4) < N)
                                sobel3(r0a.x, r0a.y, r0b.x, r1a.x, r1b.x,
                                       r2a.x, r2a.y, r2b.x, pxx0, pyy0, pxy0);
                            if ((unsigned)(bx + 2 * t - 3) < N)
                                sobel3(r0a.y, r0b.x, r0b.y, r1a.y, r1b.y,
                                       r2a.y, r2b.x, r2b.y, pxx1, pyy1, pxy1);
                        }
                        *(float2*)&ps[0][e] = make_float2(pxx0, pxx1);
                        *(float2*)&ps[1][e] = make_float2(pyy0, pyy1);
                        *(float2*)&ps[2][e] = make_float2(pxy0, pxy1);
                    }
                }
                __syncthreads();  // B2: ps ready; all xs reads of this iter done

                if (it <= RT + 4) WRITE_SLOT((it + 3) & 3, pm0, pm1, pt0, pt1)
                if (it < RT + 4) ISSUE(by + it, pm0, pm1, pt0, pt1)

                // gather window ps[2*tid .. 2*tid+9] per channel
                float q0[10], q1[10], q2[10];
                #pragma unroll
                for (int i = 0; i < 5; i++) {
                    float2 v0 = *(const float2*)&ps[0][2 * (tid + i)];
                    float2 v1 = *(const float2*)&ps[1][2 * (tid + i)];
                    float2 v2 = *(const float2*)&ps[2][2 * (tid + i)];
                    q0[2 * i] = v0.x; q0[2 * i + 1] = v0.y;
                    q1[2 * i] = v1.x; q1[2 * i + 1] = v1.y;
                    q2[2 * i] = v2.x; q2[2 * i + 1] = v2.y;
                }
                // separable gauss: horizontal 7-tap, left-assoc fp32
                float h00, h01, h10, h11, h20, h21;
                {
                    h00 = __fmul_rn(u7[0], q0[1]);
                    h01 = __fmul_rn(u7[0], q0[2]);
                    h10 = __fmul_rn(u7[0], q1[1]);
                    h11 = __fmul_rn(u7[0], q1[2]);
                    h20 = __fmul_rn(u7[0], q2[1]);
                    h21 = __fmul_rn(u7[0], q2[2]);
                    #pragma unroll
                    for (int dx = 1; dx < 7; dx++) {
                        float u = u7[dx];
                        h00 = __fadd_rn(h00, __fmul_rn(u, q0[1 + dx]));
                        h01 = __fadd_rn(h01, __fmul_rn(u, q0[2 + dx]));
                        h10 = __fadd_rn(h10, __fmul_rn(u, q1[1 + dx]));
                        h11 = __fadd_rn(h11, __fmul_rn(u, q1[2 + dx]));
                        h20 = __fadd_rn(h20, __fmul_rn(u, q2[1 + dx]));
                        h21 = __fadd_rn(h21, __fmul_rn(u, q2[2 + dx]));
                    }
                }
                // vertical ring accumulation, compile-time slots:
                // logical a[k] -> physical (j-k+7)%7
                #pragma unroll
                for (int k = 0; k < 7; k++) {
                    const int p = (j - k + 7) % 7;
                    float u = u7[k];
                    a0[p].x = __fadd_rn(a0[p].x, __fmul_rn(u, h00));
                    a0[p].y = __fadd_rn(a0[p].y, __fmul_rn(u, h01));
                    a1[p].x = __fadd_rn(a1[p].x, __fmul_rn(u, h10));
                    a1[p].y = __fadd_rn(a1[p].y, __fmul_rn(u, h11));
                    a2[p].x = __fadd_rn(a2[p].x, __fmul_rn(u, h20));
                    a2[p].y = __fadd_rn(a2[p].y, __fmul_rn(u, h21));
                }

                const int po = (j + 1) % 7;  // logical a[6] (output), then next a[0]
                int r = ri - 3;
                if (r >= by) {
                    float Rx, Ry;
                    {
                        float sx2 = a0[po].x, sy2 = a1[po].x, sxy = a2[po].x;
                        float tr = __fadd_rn(sx2, sy2);
                        float e = __fsub_rn(__fmul_rn(sx2, sy2), __fmul_rn(sxy, sxy));
                        float t3 = __fmul_rn(__fmul_rn(0.05f, tr), tr);
                        Rx = __fsub_rn(e, t3);
                    }
                    {
                        float sx2 = a0[po].y, sy2 = a1[po].y, sxy = a2[po].y;
                        float tr = __fadd_rn(sx2, sy2);
                        float e = __fsub_rn(__fmul_rn(sx2, sy2), __fmul_rn(sxy, sxy));
                        float t3 = __fmul_rn(__fmul_rn(0.05f, tr), tr);
                        Ry = __fsub_rn(e, t3);
                    }
                    *(float2*)&R[(size_t)r * N + bx + 2 * tid] = make_float2(Rx, Ry);
                    // RLE histogram: emit only on bin change
                    unsigned kx = fkey(Rx) >> 21;
                    unsigned ky = fkey(Ry) >> 21;
                    if (kx == curx) { cntx++; }
                    else { if (cntx) atomicAdd(&lh[(curx << 1) | par], cntx); curx = kx; cntx = 1; }
                    if (ky == cury) { cnty++; }
                    else { if (cnty) atomicAdd(&lh[(cury << 1) | par], cnty); cury = ky; cnty = 1; }
                }
                // recycle the output slot as next iter's a[0]
                a0[po] = make_float2(0.0f, 0.0f);
                a1[po] = make_float2(0.0f, 0.0f);
                a2[po] = make_float2(0.0f, 0.0f);

                __syncthreads();  // B1
            }
        }
    }

    // flush RLE tails, then the block histogram (sharded + rotated)
    if (cntx) atomicAdd(&lh[(curx << 1) | par], cntx);
    if (cnty) atomicAdd(&lh[(cury << 1) | par], cnty);
    __syncthreads();
    {
        const unsigned shard = (blockIdx.x + blockIdx.y) & (NSHARD - 1);
        const int rot = (int)((blockIdx.y & 31u) << 6);
        for (int i = tid; i < 2048; i += 256) {
            int r = (i + rot) & 2047;
            unsigned c = lh[2 * r] + lh[2 * r + 1];
            if (c) atomicAdd(&hist1[shard * 2048 + r], c);
        }
    }
#undef ISSUE
#undef WRITE_SLOT
}

// ============================================================
// block_select over an NSHARD-way sharded histogram: one radix-select
// pass run by one block, deterministic given identical hist contents.
// ============================================================
__device__ void block_select(const unsigned* hist, int nbins,
                             unsigned rank_in, unsigned oldpref, int shift,
                             unsigned* sc, unsigned* sres,
                             unsigned& pref_out, unsigned& rank_out) {
    const int tid = threadIdx.x;
    const int bpt = nbins >> 8;

    unsigned cnt[8];
    unsigned s = 0;
    for (int i = 0; i < bpt; i++) {
        unsigned c = 0;
        #pragma unroll
        for (int sh = 0; sh < NSHARD; sh++) c += hist[sh * nbins + tid * bpt + i];
        cnt[i] = c;
        s += c;
    }
    sc[tid] = s;
    __syncthreads();
    for (int off = 1; off < 256; off <<= 1) {
        unsigned v = (tid >= off) ? sc[tid - off] : 0u;
        __syncthreads();
        sc[tid] += v;
        __syncthreads();
    }
    const unsigned incl = sc[tid];
    const unsigned excl = incl - s;

    if (rank_in >= excl && rank_in < incl) {
        unsigned r = rank_in - excl;
        for (int i = 0; i < bpt; i++) {
            if (r < cnt[i]) {
                sres[0] = oldpref | ((unsigned)(tid * bpt + i) << shift);
                sres[1] = r;
                break;
            }
            r -= cnt[i];
        }
    }
    __syncthreads();
    pref_out = sres[0];
    rank_out = sres[1];
    __syncthreads();
}

// wave-aggregated LDS histogram add: one atomic for the leader's bin
// (the common case: ~46% of values share one bin), individual atomics
// for dissenting lanes. Counts exactly preserved.
__device__ __forceinline__ void agg_lds_add(unsigned* lh, unsigned bin, bool active) {
    unsigned long long act = __ballot(active);
    if (act == 0ull) return;
    int leader = __builtin_ctzll(act);
    unsigned lbin = __shfl(bin, leader);
    unsigned long long sm = __ballot(active && bin == lbin);
    if (active) {
        if (bin == lbin) {
            if ((int)(threadIdx.x & 63) == leader)
                atomicAdd(&lh[bin], (unsigned)__popcll(sm));
        } else {
            atomicAdd(&lh[bin], 1u);
        }
    }
}

// ============================================================
// H2: per-block select1 (sharded hist1 complete at kernel boundary),
// then stream R once -> LDS hist2 (bits 20..10 of pref1-matching
// keys, wave-aggregated), sharded flush. Block 0 publishes
// (pref1, rank1) via plain stores for H3.
// ============================================================
__global__ __launch_bounds__(256) void h2_kernel(
    const float4* __restrict__ R4, const unsigned* __restrict__ hist1,
    unsigned* __restrict__ hist2, unsigned* __restrict__ state) {
    __shared__ unsigned lh[2048];
    __shared__ unsigned sc[256];
    __shared__ unsigned sres[2];
    const int tid = threadIdx.x;

    unsigned pref1, rank1;
    block_select(hist1, 2048, MED_RANK, 0u, 21, sc, sres, pref1, rank1);
    if (blockIdx.x == 0 && tid == 0) { state[6] = pref1; state[7] = rank1; }

    for (int i = tid; i < 2048; i += 256) lh[i] = 0;
    __syncthreads();

    const int total4 = TOTAL / 4;
    const int stride = (int)gridDim.x * 256;
    for (int i = (int)blockIdx.x * 256 + tid; i < total4; i += stride) {
        float4 v = R4[i];
        unsigned kk[4];
        kk[0] = fkey(v.x); kk[1] = fkey(v.y);
        kk[2] = fkey(v.z); kk[3] = fkey(v.w);
        #pragma unroll
        for (int c = 0; c < 4; c++) {
            unsigned k = kk[c];
            bool m = (k & 0xFFE00000u) == pref1;
            agg_lds_add(lh, (k >> 10) & 0x7FFu, m);
        }
    }
    __syncthreads();
    {
        const unsigned shard = blockIdx.x & (NSHARD - 1);
        const int rot = (int)((blockIdx.x & 31u) << 6);
        for (int i = tid; i < 2048; i += 256) {
            int r = (i + rot) & 2047;
            unsigned c = lh[r];
            if (c) atomicAdd(&hist2[shard * 2048 + r], c);
        }
    }
}

// ============================================================
// H3: per-block select2 (sharded hist2 complete; pref1/rank1 from
// state), then stream R -> LDS hist3 (bits 9..0 of pref2-matching
// keys), sharded flush. Block 0 publishes (pref2, rank2) for
// maxpool's fused select3.
// ============================================================
__global__ __launch_bounds__(256) void h3_kernel(
    const float4* __restrict__ R4, const unsigned* __restrict__ hist2,
    unsigned* __restrict__ hist3, unsigned* __restrict__ state) {
    __shared__ unsigned lh[1024];
    __shared__ unsigned sc[256];
    __shared__ unsigned sres[2];
    const int tid = threadIdx.x;

    const unsigned pref1 = state[6];
    const unsigned rank1 = state[7];

    unsigned pref2, rank2;
    block_select(hist2, 2048, rank1, pref1, 10, sc, sres, pref2, rank2);
    if (blockIdx.x == 0 && tid == 0) { state[0] = pref2; state[1] = rank2; }

    for (int i = tid; i < 1024; i += 256) lh[i] = 0;
    __syncthreads();

    const int total4 = TOTAL / 4;
    const int stride = (int)gridDim.x * 256;
    for (int i = (int)blockIdx.x * 256 + tid; i < total4; i += stride) {
        float4 v = R4[i];
        unsigned kk[4];
        kk[0] = fkey(v.x); kk[1] = fkey(v.y);
        kk[2] = fkey(v.z); kk[3] = fkey(v.w);
        #pragma unroll
        for (int c = 0; c < 4; c++) {
            unsigned k = kk[c];
            bool m = (k & 0xFFFFFC00u) == pref2;
            agg_lds_add(lh, k & 0x3FFu, m);
        }
    }
    __syncthreads();
    {
        const unsigned shard = blockIdx.x & (NSHARD - 1);
        const int rot = (int)((blockIdx.x & 15u) << 6);
        for (int i = tid; i < 1024; i += 256) {
            int r = (i + rot) & 1023;
            unsigned c = lh[r];
            if (c) atomicAdd(&hist3[shard * 1024 + r], c);
        }
    }
}

// ============================================================
// K2: fused select3 (per-block, redundant, from complete sharded
// hist3) + threshold + 7x7 separable max-pool + NMS, vectorized.
// ============================================================
__global__ __launch_bounds__(256) void maxpool_kernel(
    const float* __restrict__ R, const unsigned* __restrict__ hist3,
    const unsigned* __restrict__ state, float* __restrict__ out) {
    __shared__ __align__(16) float rt[70 * 72];
    __shared__ __align__(16) float rm[70 * 64];
    __shared__ unsigned sc[256];
    __shared__ unsigned sres[2];

    const int tid = threadIdx.x;
    const int bx = blockIdx.x * 64, by = blockIdx.y * 64;

    // select pass 3 (bits 9..0), redundant per block -> median bits
    unsigned pref3, rank3;
    block_select(hist3, 1024, state[1], state[0], 0, sc, sres, pref3, rank3);
    float med;
    {
        unsigned key = pref3;
        unsigned u = (key & 0x80000000u) ? (key ^ 0x80000000u) : ~key;
        med = __uint_as_float(u);
    }

    for (int i = tid; i < 70 * 18; i += 256) {
        int r = i / 18, g = i % 18;
        int gr = by - 3 + r;
        int c0 = bx - 4 + 4 * g;
        float4 v;
        if ((unsigned)gr < N && c0 >= 0 && c0 + 3 < N) {
            v = *(const float4*)&R[(size_t)gr * N + c0];
            v.x = (v.x < med) ? 0.0f : v.x;
            v.y = (v.y < med) ? 0.0f : v.y;
            v.z = (v.z < med) ? 0.0f : v.z;
            v.w = (v.w < med) ? 0.0f : v.w;
        } else {
            float t[4];
            #pragma unroll
            for (int m = 0; m < 4; m++) {
                int c = c0 + m;
                float vv = -INFINITY;
                if ((unsigned)gr < N && (unsigned)c < N) {
                    vv = R[(size_t)gr * N + c];
                    vv = (vv < med) ? 0.0f : vv;
                }
                t[m] = vv;
            }
            v = make_float4(t[0], t[1], t[2], t[3]);
        }
        *(float4*)&rt[r * 72 + 4 * g] = v;
    }
    __syncthreads();

    for (int i = tid; i < 70 * 16; i += 256) {
        int r = i / 16, u = i % 16;
        const float* p = &rt[r * 72 + 4 * u];
        float4 A = *(const float4*)&p[0];
        float4 B = *(const float4*)&p[4];
        float4 C = *(const float4*)&p[8];
        float core = fmaxf(fmaxf(B.x, B.y), fmaxf(B.z, B.w));
        float m0 = fmaxf(fmaxf(A.y, A.z), fmaxf(A.w, core));
        float m1 = fmaxf(fmaxf(A.z, A.w), fmaxf(core, C.x));
        float m2 = fmaxf(A.w, fmaxf(core, fmaxf(C.x, C.y)));
        float m3 = fmaxf(core, fmaxf(fmaxf(C.x, C.y), C.z));
        *(float4*)&rm[r * 64 + 4 * u] = make_float4(m0, m1, m2, m3);
    }
    __syncthreads();

    for (int i = tid; i < 64 * 16; i += 256) {
        int r = i / 16, u = i % 16;
        float4 m = *(const float4*)&rm[r * 64 + 4 * u];
        #pragma unroll
        for (int dy = 1; dy < 7; dy++) {
            float4 z = *(const float4*)&rm[(r + dy) * 64 + 4 * u];
            m.x = fmaxf(m.x, z.x);
            m.y = fmaxf(m.y, z.y);
            m.z = fmaxf(m.z, z.z);
            m.w = fmaxf(m.w, z.w);
        }
        float4 v = *(const float4*)&rt[(r + 3) * 72 + 4 * u + 4];
        float4 o;
        o.x = (v.x == m.x) ? v.x : 0.0f;
        o.y = (v.y == m.y) ? v.y : 0.0f;
        o.z = (v.z == m.z) ? v.z : 0.0f;
        o.w = (v.w == m.w) ? v.w : 0.0f;
        *(float4*)&out[(size_t)(by + r) * N + bx + 4 * u] = o;
    }
}

// ============================================================
extern "C" void kernel_launch(void* const* d_in, const int* in_sizes, int n_in,
                              void* d_out, int out_size, void* d_ws, size_t ws_size,
                              hipStream_t stream) {
    const float* x = (const float*)d_in[0];
    const float* gk = (const float*)d_in[1];
    float* out = (float*)d_out;

    char* ws = (char*)d_ws;
    float* R = (float*)ws;                                 // 64 MB
    unsigned* hist1 = (unsigned*)(ws + (size_t)TOTAL * 4); // 8 x 2048 u32
    unsigned* hist2 = hist1 + NSHARD * 2048;               // 8 x 2048 u32
    unsigned* hist3 = hist2 + NSHARD * 2048;               // 8 x 1024 u32
    unsigned* state = hist3 + NSHARD * 1024;               // 8 u32:
    // [0]=pref2 [1]=rank2 [6]=pref1 [7]=rank1

    hipMemsetAsync(hist1, 0,
                   (NSHARD * (2048 + 2048 + 1024) + 8) * 4, stream);

    k1_kernel<<<dim3(N / W, N / RT), 256, 0, stream>>>(x, gk, R, hist1);

    const float4* R4 = (const float4*)R;
    h2_kernel<<<1024, 256, 0, stream>>>(R4, hist1, hist2, state);
    h3_kernel<<<1024, 256, 0, stream>>>(R4, hist2, hist3, state);

    maxpool_kernel<<<dim3(N / 64, N / 64), 256, 0, stream>>>(R, hist3, state, out);
}

// Round 13
// 240.446 us; speedup vs baseline: 1.4854x; 1.0179x over previous
//
#include <hip/hip_runtime.h>
#include <math.h>

#define N 4096
#define TOTAL (N * N)
#define MED_RANK 8388607u  // (TOTAL-1)/2
#define NSHARD 8

// monotonic float->uint key
__device__ __forceinline__ unsigned fkey(float f) {
    unsigned u = __float_as_uint(f);
    return (u & 0x80000000u) ? ~u : (u | 0x80000000u);
}

// Sobel + products — EXACT round-5-validated fp32 sequence. Do not alter.
__device__ __forceinline__ void sobel3(float A, float B, float C,
                                       float D, float F,
                                       float G, float H, float I,
                                       float& pxx, float& pyy, float& pxy) {
    float ix = __fmul_rn(-1.0f, A);
    ix = __fadd_rn(ix, C);
    ix = __fadd_rn(ix, __fmul_rn(-2.0f, D));
    ix = __fadd_rn(ix, __fmul_rn(2.0f, F));
    ix = __fadd_rn(ix, __fmul_rn(-1.0f, G));
    ix = __fadd_rn(ix, I);
    float iy = __fmul_rn(-1.0f, A);
    iy = __fadd_rn(iy, __fmul_rn(-2.0f, B));
    iy = __fadd_rn(iy, __fmul_rn(-1.0f, C));
    iy = __fadd_rn(iy, G);
    iy = __fadd_rn(iy, __fmul_rn(2.0f, H));
    iy = __fadd_rn(iy, I);
    pxx = __fmul_rn(ix, ix);
    pyy = __fmul_rn(iy, iy);
    pxy = __fmul_rn(ix, iy);
}

// ============================================================
// K1: EXACT round-11 champion (89 µs): RT=32, separable gauss
// (u = row3/sqrt(w33)), dynamic 7-ring with shift (compiler renames),
// parity-split lh, RLE hist, reg-staged async row pipeline,
// sharded+rotated flush. Do not alter.
// ============================================================
constexpr int RT = 32;
constexpr int W = 512;

__global__ __launch_bounds__(256) void k1_kernel(
    const float* __restrict__ x, const float* __restrict__ gk,
    float* __restrict__ R, unsigned* __restrict__ hist1) {
    __shared__ __align__(16) float xs[4][524];
    __shared__ __align__(16) float ps[3][520];
    __shared__ unsigned lh[4096];  // parity-split: [bin*2 + (tid&1)]

    const int tid = threadIdx.x;
    const int bx = blockIdx.x * W;
    const int by = blockIdx.y * RT;
    const unsigned par = (unsigned)(tid & 1);

    for (int i = tid; i < 4096; i += 256) lh[i] = 0;

    // separable taps: u[j] = w[3][j] / sqrt(w[3][3])
    float u7[7];
    {
        float u3 = __fsqrt_rn(gk[24]);
        #pragma unroll
        for (int j = 0; j < 7; j++) u7[j] = __fdiv_rn(gk[21 + j], u3);
    }

    float2 a0[7], a1[7], a2[7];
    #pragma unroll
    for (int k = 0; k < 7; k++) {
        a0[k] = make_float2(0.0f, 0.0f);
        a1[k] = make_float2(0.0f, 0.0f);
        a2[k] = make_float2(0.0f, 0.0f);
    }

    // RLE histogram state (per column owned by this thread)
    unsigned curx = 0xFFFFFFFFu, cntx = 0;
    unsigned cury = 0xFFFFFFFFu, cnty = 0;

    const int e_m = 2 * tid;
    const int col_m = bx - 5 + e_m;
    const int e_t = 2 * (tid + 256);
    const int col_t = bx - 5 + e_t;
    const bool has_t = (tid < 6);

#define ISSUE(arow, m0, m1, t0, t1)                                      \
    {                                                                    \
        m0 = 0.0f; m1 = 0.0f; t0 = 0.0f; t1 = 0.0f;                      \
        if ((unsigned)(arow) < N) {                                      \
            const float* xr = x + (size_t)(arow) * N;                    \
            if ((unsigned)col_m < N) m0 = xr[col_m];                     \
            if ((unsigned)(col_m + 1) < N) m1 = xr[col_m + 1];           \
            if (has_t) {                                                 \
                if ((unsigned)col_t < N) t0 = xr[col_t];                 \
                if ((unsigned)(col_t + 1) < N) t1 = xr[col_t + 1];       \
            }                                                            \
        }                                                                \
    }

#define WRITE_SLOT(slot, m0, m1, t0, t1)                                 \
    {                                                                    \
        *(float2*)&xs[slot][e_m] = make_float2(m0, m1);                  \
        if (has_t) *(float2*)&xs[slot][e_t] = make_float2(t0, t1);       \
    }

    float pm0, pm1, pt0, pt1;
    {
        float r4m0, r4m1, r4t0, r4t1;
        float r3m0, r3m1, r3t0, r3t1;
        float r2m0, r2m1, r2t0, r2t1;
        ISSUE(by - 4, r4m0, r4m1, r4t0, r4t1)
        ISSUE(by - 3, r3m0, r3m1, r3t0, r3t1)
        ISSUE(by - 2, r2m0, r2m1, r2t0, r2t1)
        ISSUE(by - 1, pm0, pm1, pt0, pt1)
        WRITE_SLOT(0, r4m0, r4m1, r4t0, r4t1)
        WRITE_SLOT(1, r3m0, r3m1, r3t0, r3t1)
        WRITE_SLOT(2, r2m0, r2m1, r2t0, r2t1)
    }
    __syncthreads();

    for (int it = 0; it < RT + 6; ++it) {
        const int ri = by - 3 + it;
        {
            const int s0 = it & 3, s1 = (it + 1) & 3, s2 = (it + 2) & 3;
            const bool rowv = (unsigned)ri < N;
            for (int t = tid; t < 260; t += 256) {
                int e = 2 * t;
                float2 r0a = *(const float2*)&xs[s0][e];
                float2 r0b = *(const float2*)&xs[s0][e + 2];
                float2 r1a = *(const float2*)&xs[s1][e];
                float2 r1b = *(const float2*)&xs[s1][e + 2];
                float2 r2a = *(const float2*)&xs[s2][e];
                float2 r2b = *(const float2*)&xs[s2][e + 2];
                float pxx0 = 0.0f, pyy0 = 0.0f, pxy0 = 0.0f;
                float pxx1 = 0.0f, pyy1 = 0.0f, pxy1 = 0.0f;
                if (rowv) {
                    if ((unsigned)(bx + 2 * t - 4) < N)
                        sobel3(r0a.x, r0a.y, r0b.x, r1a.x, r1b.x,
                               r2a.x, r2a.y, r2b.x, pxx0, pyy0, pxy0);
                    if ((unsigned)(bx + 2 * t - 3) < N)
                        sobel3(r0a.y, r0b.x, r0b.y, r1a.y, r1b.y,
                               r2a.y, r2b.x, r2b.y, pxx1, pyy1, pxy1);
                }
                *(float2*)&ps[0][e] = make_float2(pxx0, pxx1);
                *(float2*)&ps[1][e] = make_float2(pyy0, pyy1);
                *(float2*)&ps[2][e] = make_float2(pxy0, pxy1);
            }
        }
        __syncthreads();  // B2: ps ready; all xs reads of this iter done

        if (it <= RT + 4) WRITE_SLOT((it + 3) & 3, pm0, pm1, pt0, pt1)
        if (it < RT + 4) ISSUE(by + it, pm0, pm1, pt0, pt1)

        // gather window ps[2*tid .. 2*tid+9] per channel
        float q0[10], q1[10], q2[10];
        #pragma unroll
        for (int i = 0; i < 5; i++) {
            float2 v0 = *(const float2*)&ps[0][2 * (tid + i)];
            float2 v1 = *(const float2*)&ps[1][2 * (tid + i)];
            float2 v2 = *(const float2*)&ps[2][2 * (tid + i)];
            q0[2 * i] = v0.x; q0[2 * i + 1] = v0.y;
            q1[2 * i] = v1.x; q1[2 * i + 1] = v1.y;
            q2[2 * i] = v2.x; q2[2 * i + 1] = v2.y;
        }
        // separable gauss: horizontal 7-tap, left-assoc fp32
        float h00, h01, h10, h11, h20, h21;
        {
            h00 = __fmul_rn(u7[0], q0[1]);
            h01 = __fmul_rn(u7[0], q0[2]);
            h10 = __fmul_rn(u7[0], q1[1]);
            h11 = __fmul_rn(u7[0], q1[2]);
            h20 = __fmul_rn(u7[0], q2[1]);
            h21 = __fmul_rn(u7[0], q2[2]);
            #pragma unroll
            for (int dx = 1; dx < 7; dx++) {
                float u = u7[dx];
                h00 = __fadd_rn(h00, __fmul_rn(u, q0[1 + dx]));
                h01 = __fadd_rn(h01, __fmul_rn(u, q0[2 + dx]));
                h10 = __fadd_rn(h10, __fmul_rn(u, q1[1 + dx]));
                h11 = __fadd_rn(h11, __fmul_rn(u, q1[2 + dx]));
                h20 = __fadd_rn(h20, __fmul_rn(u, q2[1 + dx]));
                h21 = __fadd_rn(h21, __fmul_rn(u, q2[2 + dx]));
            }
        }
        #pragma unroll
        for (int k = 0; k < 7; k++) {
            float u = u7[k];
            a0[k].x = __fadd_rn(a0[k].x, __fmul_rn(u, h00));
            a0[k].y = __fadd_rn(a0[k].y, __fmul_rn(u, h01));
            a1[k].x = __fadd_rn(a1[k].x, __fmul_rn(u, h10));
            a1[k].y = __fadd_rn(a1[k].y, __fmul_rn(u, h11));
            a2[k].x = __fadd_rn(a2[k].x, __fmul_rn(u, h20));
            a2[k].y = __fadd_rn(a2[k].y, __fmul_rn(u, h21));
        }

        int r = ri - 3;
        if (r >= by) {
            float Rx, Ry;
            {
                float sx2 = a0[6].x, sy2 = a1[6].x, sxy = a2[6].x;
                float tr = __fadd_rn(sx2, sy2);
                float e = __fsub_rn(__fmul_rn(sx2, sy2), __fmul_rn(sxy, sxy));
                float t3 = __fmul_rn(__fmul_rn(0.05f, tr), tr);
                Rx = __fsub_rn(e, t3);
            }
            {
                float sx2 = a0[6].y, sy2 = a1[6].y, sxy = a2[6].y;
                float tr = __fadd_rn(sx2, sy2);
                float e = __fsub_rn(__fmul_rn(sx2, sy2), __fmul_rn(sxy, sxy));
                float t3 = __fmul_rn(__fmul_rn(0.05f, tr), tr);
                Ry = __fsub_rn(e, t3);
            }
            *(float2*)&R[(size_t)r * N + bx + 2 * tid] = make_float2(Rx, Ry);
            // RLE histogram: emit only on bin change
            unsigned kx = fkey(Rx) >> 21;
            unsigned ky = fkey(Ry) >> 21;
            if (kx == curx) { cntx++; }
            else { if (cntx) atomicAdd(&lh[(curx << 1) | par], cntx); curx = kx; cntx = 1; }
            if (ky == cury) { cnty++; }
            else { if (cnty) atomicAdd(&lh[(cury << 1) | par], cnty); cury = ky; cnty = 1; }
        }
        #pragma unroll
        for (int k = 6; k > 0; k--) { a0[k] = a0[k - 1]; a1[k] = a1[k - 1]; a2[k] = a2[k - 1]; }
        a0[0] = make_float2(0.0f, 0.0f);
        a1[0] = make_float2(0.0f, 0.0f);
        a2[0] = make_float2(0.0f, 0.0f);

        __syncthreads();  // B1
    }

    // flush RLE tails, then the block histogram (sharded + rotated)
    if (cntx) atomicAdd(&lh[(curx << 1) | par], cntx);
    if (cnty) atomicAdd(&lh[(cury << 1) | par], cnty);
    __syncthreads();
    {
        const unsigned shard = (blockIdx.x + blockIdx.y) & (NSHARD - 1);
        const int rot = (int)((blockIdx.y & 31u) << 6);
        for (int i = tid; i < 2048; i += 256) {
            int r = (i + rot) & 2047;
            unsigned c = lh[2 * r] + lh[2 * r + 1];
            if (c) atomicAdd(&hist1[shard * 2048 + r], c);
        }
    }
#undef ISSUE
#undef WRITE_SLOT
}

// ============================================================
// block_select over a PLAIN (unsharded) histogram.
// ============================================================
__device__ void block_select(const unsigned* hist, int nbins,
                             unsigned rank_in, unsigned oldpref, int shift,
                             unsigned* sc, unsigned* sres,
                             unsigned& pref_out, unsigned& rank_out) {
    const int tid = threadIdx.x;
    const int bpt = nbins >> 8;

    unsigned cnt[8];
    unsigned s = 0;
    for (int i = 0; i < bpt; i++) { cnt[i] = hist[tid * bpt + i]; s += cnt[i]; }
    sc[tid] = s;
    __syncthreads();
    for (int off = 1; off < 256; off <<= 1) {
        unsigned v = (tid >= off) ? sc[tid - off] : 0u;
        __syncthreads();
        sc[tid] += v;
        __syncthreads();
    }
    const unsigned incl = sc[tid];
    const unsigned excl = incl - s;

    if (rank_in >= excl && rank_in < incl) {
        unsigned r = rank_in - excl;
        for (int i = 0; i < bpt; i++) {
            if (r < cnt[i]) {
                sres[0] = oldpref | ((unsigned)(tid * bpt + i) << shift);
                sres[1] = r;
                break;
            }
            r -= cnt[i];
        }
    }
    __syncthreads();
    pref_out = sres[0];
    rank_out = sres[1];
    __syncthreads();
}

// block_select over an NSHARD-way sharded histogram.
__device__ void block_select_sh8(const unsigned* hist, int nbins,
                                 unsigned rank_in, unsigned oldpref, int shift,
                                 unsigned* sc, unsigned* sres,
                                 unsigned& pref_out, unsigned& rank_out) {
    const int tid = threadIdx.x;
    const int bpt = nbins >> 8;

    unsigned cnt[8];
    unsigned s = 0;
    for (int i = 0; i < bpt; i++) {
        unsigned c = 0;
        #pragma unroll
        for (int sh = 0; sh < NSHARD; sh++) c += hist[sh * nbins + tid * bpt + i];
        cnt[i] = c;
        s += c;
    }
    sc[tid] = s;
    __syncthreads();
    for (int off = 1; off < 256; off <<= 1) {
        unsigned v = (tid >= off) ? sc[tid - off] : 0u;
        __syncthreads();
        sc[tid] += v;
        __syncthreads();
    }
    const unsigned incl = sc[tid];
    const unsigned excl = incl - s;

    if (rank_in >= excl && rank_in < incl) {
        unsigned r = rank_in - excl;
        for (int i = 0; i < bpt; i++) {
            if (r < cnt[i]) {
                sres[0] = oldpref | ((unsigned)(tid * bpt + i) << shift);
                sres[1] = r;
                break;
            }
            r -= cnt[i];
        }
    }
    __syncthreads();
    pref_out = sres[0];
    rank_out = sres[1];
    __syncthreads();
}

// wave-aggregated LDS histogram add (kept for h3 where the act==0
// early-out skips ~99.97% of elements).
__device__ __forceinline__ void agg_lds_add(unsigned* lh, unsigned bin, bool active) {
    unsigned long long act = __ballot(active);
    if (act == 0ull) return;
    int leader = __builtin_ctzll(act);
    unsigned lbin = __shfl(bin, leader);
    unsigned long long sm = __ballot(active && bin == lbin);
    if (active) {
        if (bin == lbin) {
            if ((int)(threadIdx.x & 63) == leader)
                atomicAdd(&lh[bin], (unsigned)__popcll(sm));
        } else {
            atomicAdd(&lh[bin], 1u);
        }
    }
}

// ============================================================
// H2: per-block select1 (sharded hist1), then stream R once ->
// LDS hist2 (bits 20..10 of pref1-matching keys, PLAIN atomics —
// bins are mantissa bits, well spread; the ballot aggregation cost
// more than the contention it saved), sharded flush. Block 0
// publishes (pref1, rank1) via plain stores for H3.
// ============================================================
__global__ __launch_bounds__(256) void h2_kernel(
    const float4* __restrict__ R4, const unsigned* __restrict__ hist1,
    unsigned* __restrict__ hist2, unsigned* __restrict__ state) {
    __shared__ unsigned lh[2048];
    __shared__ unsigned sc[256];
    __shared__ unsigned sres[2];
    const int tid = threadIdx.x;

    unsigned pref1, rank1;
    block_select_sh8(hist1, 2048, MED_RANK, 0u, 21, sc, sres, pref1, rank1);
    if (blockIdx.x == 0 && tid == 0) { state[6] = pref1; state[7] = rank1; }

    for (int i = tid; i < 2048; i += 256) lh[i] = 0;
    __syncthreads();

    const int total4 = TOTAL / 4;
    const int stride = (int)gridDim.x * 256;
    for (int i = (int)blockIdx.x * 256 + tid; i < total4; i += stride) {
        float4 v = R4[i];
        unsigned kk[4];
        kk[0] = fkey(v.x); kk[1] = fkey(v.y);
        kk[2] = fkey(v.z); kk[3] = fkey(v.w);
        #pragma unroll
        for (int c = 0; c < 4; c++) {
            unsigned k = kk[c];
            if ((k & 0xFFE00000u) == pref1)
                atomicAdd(&lh[(k >> 10) & 0x7FFu], 1u);
        }
    }
    __syncthreads();
    {
        const unsigned shard = blockIdx.x & (NSHARD - 1);
        const int rot = (int)((blockIdx.x & 31u) << 6);
        for (int i = tid; i < 2048; i += 256) {
            int r = (i + rot) & 2047;
            unsigned c = lh[r];
            if (c) atomicAdd(&hist2[shard * 2048 + r], c);
        }
    }
}

// ============================================================
// H3: per-block select2 (sharded hist2; pref1/rank1 from state),
// then stream R -> LDS hist3 (bits 9..0 of pref2-matching keys,
// wave-aggregated: ~0.03% match so the act==0 early-out wins),
// UNSHARDED flush (sparse: only a handful of nonzero bins/block).
// Block 0 publishes (pref2, rank2) for maxpool's fused select3.
// ============================================================
__global__ __launch_bounds__(256) void h3_kernel(
    const float4* __restrict__ R4, const unsigned* __restrict__ hist2,
    unsigned* __restrict__ hist3, unsigned* __restrict__ state) {
    __shared__ unsigned lh[1024];
    __shared__ unsigned sc[256];
    __shared__ unsigned sres[2];
    const int tid = threadIdx.x;

    const unsigned pref1 = state[6];
    const unsigned rank1 = state[7];

    unsigned pref2, rank2;
    block_select_sh8(hist2, 2048, rank1, pref1, 10, sc, sres, pref2, rank2);
    if (blockIdx.x == 0 && tid == 0) { state[0] = pref2; state[1] = rank2; }

    for (int i = tid; i < 1024; i += 256) lh[i] = 0;
    __syncthreads();

    const int total4 = TOTAL / 4;
    const int stride = (int)gridDim.x * 256;
    for (int i = (int)blockIdx.x * 256 + tid; i < total4; i += stride) {
        float4 v = R4[i];
        unsigned kk[4];
        kk[0] = fkey(v.x); kk[1] = fkey(v.y);
        kk[2] = fkey(v.z); kk[3] = fkey(v.w);
        #pragma unroll
        for (int c = 0; c < 4; c++) {
            unsigned k = kk[c];
            bool m = (k & 0xFFFFFC00u) == pref2;
            agg_lds_add(lh, k & 0x3FFu, m);
        }
    }
    __syncthreads();
    // unsharded flush: hist3 is sparse (~4.6K total counts over 1024 bins)
    for (int i = tid; i < 1024; i += 256) {
        unsigned c = lh[i];
        if (c) atomicAdd(&hist3[i], c);
    }
}

// ============================================================
// K2: fused select3 (per-block, redundant, from complete UNSHARDED
// hist3 — 4 KB/block instead of 32 KB) + threshold + 7x7 separable
// max-pool + NMS, vectorized.
// ============================================================
__global__ __launch_bounds__(256) void maxpool_kernel(
    const float* __restrict__ R, const unsigned* __restrict__ hist3,
    const unsigned* __restrict__ state, float* __restrict__ out) {
    __shared__ __align__(16) float rt[70 * 72];
    __shared__ __align__(16) float rm[70 * 64];
    __shared__ unsigned sc[256];
    __shared__ unsigned sres[2];

    const int tid = threadIdx.x;
    const int bx = blockIdx.x * 64, by = blockIdx.y * 64;

    // select pass 3 (bits 9..0), redundant per block -> median bits
    unsigned pref3, rank3;
    block_select(hist3, 1024, state[1], state[0], 0, sc, sres, pref3, rank3);
    float med;
    {
        unsigned key = pref3;
        unsigned u = (key & 0x80000000u) ? (key ^ 0x80000000u) : ~key;
        med = __uint_as_float(u);
    }

    for (int i = tid; i < 70 * 18; i += 256) {
        int r = i / 18, g = i % 18;
        int gr = by - 3 + r;
        int c0 = bx - 4 + 4 * g;
        float4 v;
        if ((unsigned)gr < N && c0 >= 0 && c0 + 3 < N) {
            v = *(const float4*)&R[(size_t)gr * N + c0];
            v.x = (v.x < med) ? 0.0f : v.x;
            v.y = (v.y < med) ? 0.0f : v.y;
            v.z = (v.z < med) ? 0.0f : v.z;
            v.w = (v.w < med) ? 0.0f : v.w;
        } else {
            float t[4];
            #pragma unroll
            for (int m = 0; m < 4; m++) {
                int c = c0 + m;
                float vv = -INFINITY;
                if ((unsigned)gr < N && (unsigned)c < N) {
                    vv = R[(size_t)gr * N + c];
                    vv = (vv < med) ? 0.0f : vv;
                }
                t[m] = vv;
            }
            v = make_float4(t[0], t[1], t[2], t[3]);
        }
        *(float4*)&rt[r * 72 + 4 * g] = v;
    }
    __syncthreads();

    for (int i = tid; i < 70 * 16; i += 256) {
        int r = i / 16, u = i % 16;
        const float* p = &rt[r * 72 + 4 * u];
        float4 A = *(const float4*)&p[0];
        float4 B = *(const float4*)&p[4];
        float4 C = *(const float4*)&p[8];
        float core = fmaxf(fmaxf(B.x, B.y), fmaxf(B.z, B.w));
        float m0 = fmaxf(fmaxf(A.y, A.z), fmaxf(A.w, core));
        float m1 = fmaxf(fmaxf(A.z, A.w), fmaxf(core, C.x));
        float m2 = fmaxf(A.w, fmaxf(core, fmaxf(C.x, C.y)));
        float m3 = fmaxf(core, fmaxf(fmaxf(C.x, C.y), C.z));
        *(float4*)&rm[r * 64 + 4 * u] = make_float4(m0, m1, m2, m3);
    }
    __syncthreads();

    for (int i = tid; i < 64 * 16; i += 256) {
        int r = i / 16, u = i % 16;
        float4 m = *(const float4*)&rm[r * 64 + 4 * u];
        #pragma unroll
        for (int dy = 1; dy < 7; dy++) {
            float4 z = *(const float4*)&rm[(r + dy) * 64 + 4 * u];
            m.x = fmaxf(m.x, z.x);
            m.y = fmaxf(m.y, z.y);
            m.z = fmaxf(m.z, z.z);
            m.w = fmaxf(m.w, z.w);
        }
        float4 v = *(const float4*)&rt[(r + 3) * 72 + 4 * u + 4];
        float4 o;
        o.x = (v.x == m.x) ? v.x : 0.0f;
        o.y = (v.y == m.y) ? v.y : 0.0f;
        o.z = (v.z == m.z) ? v.z : 0.0f;
        o.w = (v.w == m.w) ? v.w : 0.0f;
        *(float4*)&out[(size_t)(by + r) * N + bx + 4 * u] = o;
    }
}

// ============================================================
extern "C" void kernel_launch(void* const* d_in, const int* in_sizes, int n_in,
                              void* d_out, int out_size, void* d_ws, size_t ws_size,
                              hipStream_t stream) {
    const float* x = (const float*)d_in[0];
    const float* gk = (const float*)d_in[1];
    float* out = (float*)d_out;

    char* ws = (char*)d_ws;
    float* R = (float*)ws;                                 // 64 MB
    unsigned* hist1 = (unsigned*)(ws + (size_t)TOTAL * 4); // 8 x 2048 u32
    unsigned* hist2 = hist1 + NSHARD * 2048;               // 8 x 2048 u32
    unsigned* hist3 = hist2 + NSHARD * 2048;               // 1024 u32 (unsharded)
    unsigned* state = hist3 + 1024;                        // 8 u32:
    // [0]=pref2 [1]=rank2 [6]=pref1 [7]=rank1

    hipMemsetAsync(hist1, 0,
                   (NSHARD * (2048 + 2048) + 1024 + 8) * 4, stream);

    k1_kernel<<<dim3(N / W, N / RT), 256, 0, stream>>>(x, gk, R, hist1);

    const float4* R4 = (const float4*)R;
    h2_kernel<<<1024, 256, 0, stream>>>(R4, hist1, hist2, state);
    h3_kernel<<<1024, 256, 0, stream>>>(R4, hist2, hist3, state);

    maxpool_kernel<<<dim3(N / 64, N / 64), 256, 0, stream>>>(R, hist3, state, out);
}